// Round 5
// baseline (250.310 us; speedup 1.0000x reference)
//
#include <hip/hip_runtime.h>
#include <cstdint>
#include <cstddef>

// ---------- types ----------
using short8_t = __attribute__((ext_vector_type(8))) short;
using f32x4    = __attribute__((ext_vector_type(4))) float;
typedef unsigned short bfu16;

constexpr int   Nn   = 16;
constexpr int   Tt   = 1024;
constexpr int   IDIM = 512;
constexpr int   Vv   = 4096;
constexpr int   Ss   = 128;
constexpr int   Ll   = 2 * Ss + 1;   // 257
constexpr int   LS   = 132;          // plab row stride (pad 129 -> 132)
constexpr float NEGV = -1e30f;
constexpr float L2E  = 1.4426950408889634f;  // log2(e)
constexpr float LN2  = 0.6931471805599453f;  // ln(2)

// ---------- helpers ----------
__device__ __forceinline__ float fexp2(float x) { return __builtin_amdgcn_exp2f(x); }
__device__ __forceinline__ float flog2(float x) { return __builtin_amdgcn_logf(x); }

__device__ __forceinline__ bfu16 f2bf(float f) {
  unsigned int x = __float_as_uint(f);
  x = x + 0x7fffu + ((x >> 16) & 1u);   // RNE (inputs are finite normals)
  return (bfu16)(x >> 16);
}

__device__ __forceinline__ void async16(const void* g, void* l) {
  __builtin_amdgcn_global_load_lds(
      (__attribute__((address_space(1))) void*)(g),
      (__attribute__((address_space(3))) void*)(l), 16, 0, 0);
}

// ---------- kernel 1: fp32 -> bf16 convert + zero output ----------
__global__ void convert_zero(const float4* __restrict__ hs4,
                             const float4* __restrict__ W4,
                             ushort4* __restrict__ hsb4,
                             ushort4* __restrict__ Wb4,
                             float* __restrict__ out) {
  if (blockIdx.x == 0 && threadIdx.x == 0) out[0] = 0.f;
  const int HS4 = (Nn * Tt * IDIM) / 4;        // 2097152
  const int TOT = HS4 + (Vv * IDIM) / 4;       // +524288
  for (int i = blockIdx.x * 256 + threadIdx.x; i < TOT; i += gridDim.x * 256) {
    float4 f;
    if (i < HS4) f = hs4[i]; else f = W4[i - HS4];
    ushort4 o;
    o.x = f2bf(f.x); o.y = f2bf(f.y); o.z = f2bf(f.z); o.w = f2bf(f.w);
    if (i < HS4) hsb4[i] = o; else Wb4[i - HS4] = o;
  }
}

// ---------- kernel 2: build label map / extended sequence ----------
__global__ void build_labels(const int* __restrict__ ys,
                             int* __restrict__ labmap,
                             int* __restrict__ extidx,
                             int* __restrict__ skipflag) {
  const int n = blockIdx.x, tid = threadIdx.x;
  int* lm = labmap + n * Vv;
  for (int v = tid; v < Vv; v += 256) lm[v] = 0x7fffffff;
  __syncthreads();
  if (tid == 0) lm[0] = 0;                                  // blank -> slot 0
  if (tid < Ss) atomicMin(&lm[ys[n * Ss + tid]], tid + 1);  // canonical = first occurrence
  __syncthreads();
  for (int s = tid; s < Ll; s += 256) {
    int v = (s & 1) ? ys[n * Ss + ((s - 1) >> 1)] : 0;
    extidx[n * Ll + s] = lm[v];
    int allow = 0;
    if ((s & 1) && s >= 3) allow = (v != ys[n * Ss + ((s - 3) >> 1)]) ? 1 : 0;
    skipflag[n * Ll + s] = allow;
  }
  __syncthreads();
  for (int v = tid; v < Vv; v += 256)
    if (lm[v] == 0x7fffffff) lm[v] = -1;
}

// ---------- kernel 3: bf16 MFMA GEMM fused with lse partials + label scatter ----------
// LDS chunk-XOR swizzle (chunk ^= (row>>1)&3) applied via pre-swizzled global
// source (global_load_lds writes linearly) + swizzled ds_read address.
// Double-buffered LDS, one barrier per K-step (2-phase pipeline).
__global__ __launch_bounds__(256) void gemm_lse(
    const bfu16* __restrict__ A,      // [16384][512] hs bf16
    const bfu16* __restrict__ B,      // [4096][512]  W  bf16 (B^T layout)
    const float* __restrict__ bias,   // [4096]
    const int*   __restrict__ labmap, // [16][4096]
    float* __restrict__ plab,         // [16384][LS]  exp2(logit*L2E) at label slots
    float* __restrict__ pmax,         // [64][16384]
    float* __restrict__ psum) {       // [64][16384]
  __shared__ bfu16 ldsA[2 * 128 * 32];    // 16 KB (double-buffered)
  __shared__ bfu16 ldsB[2 * 128 * 32];    // 16 KB
  const int bR = blockIdx.x, bC = blockIdx.y;
  const int rowbase = bR * 128, colbase = bC * 128;
  const int tid  = threadIdx.x;
  const int lane = tid & 63, wid = tid >> 6;
  const int wr = wid >> 1, wc = wid & 1;

  f32x4 acc[4][4];
#pragma unroll
  for (int m = 0; m < 4; m++)
#pragma unroll
    for (int n = 0; n < 4; n++) {
      f32x4 z = {0.f, 0.f, 0.f, 0.f};
      acc[m][n] = z;
    }

  // ---- staging addresses (pre-swizzled source chunk) ----
  // lane l writes LDS row (wid*32 + (l>>2)) chunk (l&3); source chunk is
  // (l&3) ^ ((l>>3)&3) so that LDS(row,c) = global(row, c ^ ((row>>1)&3)).
  const int r16 = lane >> 2;                       // 0..15
  const int scb = (((lane & 3) ^ ((lane >> 3) & 3))) * 16;  // swizzled src chunk bytes
  const char* gA0 = (const char*)(A + (size_t)(rowbase + wid * 32 + r16) * IDIM) + scb;
  const char* gB0 = (const char*)(B + (size_t)(colbase + wid * 32 + r16) * IDIM) + scb;
  char* dA = (char*)ldsA + wid * 2048;
  char* dB = (char*)ldsB + wid * 2048;

  // ---- fragment-read addresses (swizzled chunk) ----
  const int fr  = lane & 15;
  const int rdB = (((lane >> 4) ^ ((fr >> 1) & 3))) * 16;   // swizzled chunk bytes

  // prefetch epilogue metadata early (latency hidden under K-loop)
  const int nsamp = bR >> 3;
  const int* lm = labmap + nsamp * Vv;
  float bc[4];
  int   slot[4];
#pragma unroll
  for (int n = 0; n < 4; n++) {
    int c = colbase + wc * 64 + n * 16 + fr;
    bc[n]   = bias[c];
    slot[n] = lm[c];
  }

  auto stage = [&](int buf, int k0) {
    const char* ga = gA0 + k0 * 2;
    const char* gb = gB0 + k0 * 2;
    char* da = dA + buf * 8192;
    char* db = dB + buf * 8192;
    async16(ga,         da);
    async16(ga + 16384, da + 1024);   // +16 rows (16*512*2 bytes)
    async16(gb,         db);
    async16(gb + 16384, db + 1024);
  };

  stage(0, 0);
  __syncthreads();                    // drain prologue stage

  int buf = 0;
  for (int it = 0; it < 16; ++it) {
    if (it < 15) stage(buf ^ 1, (it + 1) * 32);   // prefetch next K-tile

    const char* lA = (const char*)ldsA + buf * 8192;
    const char* lB = (const char*)ldsB + buf * 8192;
    short8_t af[4], bfr[4];
#pragma unroll
    for (int m = 0; m < 4; m++)
      af[m] = *(const short8_t*)(lA + (wr * 64 + m * 16 + fr) * 64 + rdB);
#pragma unroll
    for (int n = 0; n < 4; n++)
      bfr[n] = *(const short8_t*)(lB + (wc * 64 + n * 16 + fr) * 64 + rdB);

#pragma unroll
    for (int m = 0; m < 4; m++)
#pragma unroll
      for (int n = 0; n < 4; n++)
        acc[m][n] = __builtin_amdgcn_mfma_f32_16x16x32_bf16(af[m], bfr[n], acc[m][n], 0, 0, 0);

    __syncthreads();                  // drains prefetch vmcnt + protects LDS reuse
    buf ^= 1;
  }

  // ---- epilogue: bias, label scatter (exp2'd), max-first lse partials ----
  const int g4 = (lane >> 4) * 4;

#pragma unroll
  for (int m = 0; m < 4; m++) {
#pragma unroll
    for (int r = 0; r < 4; r++) {
      int row = rowbase + wr * 64 + m * 16 + g4 + r;
      float v0 = acc[m][0][r] + bc[0];
      float v1 = acc[m][1][r] + bc[1];
      float v2 = acc[m][2][r] + bc[2];
      float v3 = acc[m][3][r] + bc[3];
      if (slot[0] >= 0) plab[(size_t)row * LS + slot[0]] = fexp2(v0 * L2E);
      if (slot[1] >= 0) plab[(size_t)row * LS + slot[1]] = fexp2(v1 * L2E);
      if (slot[2] >= 0) plab[(size_t)row * LS + slot[2]] = fexp2(v2 * L2E);
      if (slot[3] >= 0) plab[(size_t)row * LS + slot[3]] = fexp2(v3 * L2E);
      // max-first two-phase reduce across the 16-lane column group
      float mx = fmaxf(fmaxf(v0, v1), fmaxf(v2, v3));
#pragma unroll
      for (int off = 1; off < 16; off <<= 1)
        mx = fmaxf(mx, __shfl_xor(mx, off));
      float sm = fexp2((v0 - mx) * L2E) + fexp2((v1 - mx) * L2E) +
                 fexp2((v2 - mx) * L2E) + fexp2((v3 - mx) * L2E);
#pragma unroll
      for (int off = 1; off < 16; off <<= 1)
        sm += __shfl_xor(sm, off);
      if (fr == 0) {
        int pc = bC * 2 + wc;             // 0..63
        pmax[(size_t)pc * 16384 + row] = mx;
        psum[(size_t)pc * 16384 + row] = sm;
      }
    }
  }
}

// ---------- kernel 4: reduce 64 lse partials per row ----------
__global__ void lse_reduce(const float* __restrict__ pmax,
                           const float* __restrict__ psum,
                           float* __restrict__ lse) {
  int row = blockIdx.x * 256 + threadIdx.x;
  float m = NEGV, s = 0.f;
#pragma unroll 8
  for (int j = 0; j < 64; j++) {
    float pm = pmax[(size_t)j * 16384 + row];
    float ps = psum[(size_t)j * 16384 + row];
    float nm = fmaxf(m, pm);
    s = s * __expf(m - nm) + ps * __expf(pm - nm);
    m = nm;
  }
  lse[row] = m + __logf(s);
}

// ---------- kernel 5: CTC forward DP, one wave per sample ----------
// LINEAR-domain DP on raw-logit probabilities p = 2^(logit*L2E), with
// wave-uniform power-of-2 rescaling every 16 steps. Zero transcendentals
// in the serial loop. lse correction applied once at the end.
constexpr int DPD = 8;   // prefetch depth

__global__ __launch_bounds__(64) void ctc_dp(
    const float* __restrict__ plab, const float* __restrict__ lse,
    const int* __restrict__ extidx, const int* __restrict__ skipflag,
    const int* __restrict__ hlens, const int* __restrict__ ylens,
    float* __restrict__ out) {
  const int n    = blockIdx.x;
  const int lane = threadIdx.x;
  const int hlen = hlens[n];
  const int Ln   = 2 * ylens[n] + 1;
  const int sbase = lane * 4;   // states sbase..sbase+3; lane 63 also owns s=256

  // per-lane static DP metadata (even states are blanks since sbase is even)
  const int   e1  = extidx[n * Ll + sbase + 1];
  const int   e3  = extidx[n * Ll + sbase + 3];
  const float sk1 = skipflag[n * Ll + sbase + 1] ? 1.f : 0.f;
  const float sk3 = skipflag[n * Ll + sbase + 3] ? 1.f : 0.f;
  const float m0  = (sbase + 0 < Ln) ? 1.f : 0.f;
  const float m1  = (sbase + 1 < Ln) ? 1.f : 0.f;
  const float m2  = (sbase + 2 < Ln) ? 1.f : 0.f;
  const float m3  = (sbase + 3 < Ln) ? 1.f : 0.f;
  const float m4  = (lane == 63 && Ln == 257) ? 1.f : 0.f;

  const float* pl  = plab + (size_t)n * Tt * LS;
  const float* lsp = lse + n * Tt;

  // sum of lse over t < hlen (uniform across states -> applied once at end)
  float slse = 0.f;
  for (int t = lane; t < hlen; t += 64) slse += lsp[t];
#pragma unroll
  for (int off = 32; off; off >>= 1) slse += __shfl_xor(slse, off);

  // t = 0 init: alpha[0] = p_blank(0), alpha[1] = p_y1(0)
  float a0 = 0.f, a1 = 0.f, a2 = 0.f, a3 = 0.f, a4 = 0.f;
  if (lane == 0) { a0 = pl[0]; a1 = pl[e1]; }

  int sc = 0;   // accumulated log2 scale (true alpha = stored * 2^sc)

  auto step = [&](float pb, float p1, float p3) {
    float pm1 = __shfl_up(a3, 1);      // alpha[sbase-1]
    float pm2 = __shfl_up(a2, 1);      // alpha[sbase-2]
    pm1 = (lane == 0) ? 0.f : pm1;
    pm2 = (lane == 0) ? 0.f : pm2;
    float n4 = (a4 + a3) * pb * m4;                 // s=256 (blank), lane 63 only
    float n3 = (a3 + a2 + sk3 * a1)  * p3 * m3;     // odd (label)
    float n2 = (a2 + a1)             * pb * m2;     // even (blank)
    float n1 = (a1 + a0 + sk1 * pm2) * p1 * m1;     // odd (label)
    float n0 = (a0 + pm1)            * pb * m0;     // even (blank)
    a0 = n0; a1 = n1; a2 = n2; a3 = n3; a4 = n4;
  };

  auto rescale = [&]() {
    float mx = fmaxf(fmaxf(a0, a1), fmaxf(a2, a3));
    mx = fmaxf(mx, a4);
#pragma unroll
    for (int off = 32; off; off >>= 1) mx = fmaxf(mx, __shfl_xor(mx, off));
    int ee = (int)((__float_as_uint(mx) >> 23) & 0xff) - 127;   // floor(log2 mx)
    ee = (mx > 0.f) ? ee : 0;
    float s = __uint_as_float((unsigned)(127 - ee) << 23);      // 2^(-ee)
    sc += ee;
    a0 *= s; a1 *= s; a2 *= s; a3 *= s; a4 *= s;
  };

  // preload prefetch ring for t = 1..DPD (1 uniform blank + 2 gathers per row)
  float rb[DPD], r1[DPD], r3[DPD];
#pragma unroll
  for (int d = 0; d < DPD; d++) {
    int tt = 1 + d;
    rb[d] = pl[(size_t)tt * LS];
    r1[d] = pl[(size_t)tt * LS + e1];
    r3[d] = pl[(size_t)tt * LS + e3];
  }

  const int nfull = (hlen - 1) / DPD;
  for (int b = 0; b < nfull; b++) {
    const int t0 = 1 + b * DPD;
#pragma unroll
    for (int d = 0; d < DPD; d++) {
      float pb = rb[d], p1 = r1[d], p3 = r3[d];
      int tn = t0 + d + DPD;
      if (tn > Tt - 1) tn = Tt - 1;    // clamp keeps loads in-bounds
      rb[d] = pl[(size_t)tn * LS];
      r1[d] = pl[(size_t)tn * LS + e1];
      r3[d] = pl[(size_t)tn * LS + e3];
      step(pb, p1, p3);
    }
    if ((b & 1) || b == nfull - 1) rescale();   // every 16 steps + final block
  }
  // tail (< DPD steps): direct loads
  for (int t = 1 + nfull * DPD; t < hlen; t++) {
    step(pl[(size_t)t * LS], pl[(size_t)t * LS + e1], pl[(size_t)t * LS + e3]);
  }

  __shared__ float alf[264];
  alf[sbase + 0] = a0; alf[sbase + 1] = a1;
  alf[sbase + 2] = a2; alf[sbase + 3] = a3;
  if (lane == 63) alf[256] = a4;
  __syncthreads();
  if (lane == 0) {
    float sum = alf[Ln - 1] + alf[Ln - 2];
    float per = 0.f;
    if (sum > 0.f) {
      float llv = (flog2(sum) + (float)sc) * LN2 - slse;
      if (llv > -1e29f) per = -llv;
    }
    atomicAdd(out, per * (1.0f / 16.0f));
  }
}

// ---------- launcher ----------
extern "C" void kernel_launch(void* const* d_in, const int* in_sizes, int n_in,
                              void* d_out, int out_size, void* d_ws, size_t ws_size,
                              hipStream_t stream) {
  const float* hs    = (const float*)d_in[0];
  const int*   hlens = (const int*)d_in[1];
  const int*   ys    = (const int*)d_in[2];
  const int*   ylens = (const int*)d_in[3];
  const float* W     = (const float*)d_in[4];
  const float* bias  = (const float*)d_in[5];
  float*       out   = (float*)d_out;
  char*        ws    = (char*)d_ws;

  // workspace carve (bytes)
  const size_t off_hsb    = 0;                               // 16,777,216
  const size_t off_Wb     = off_hsb    + (size_t)Nn*Tt*IDIM*2;
  const size_t off_plab   = off_Wb     + (size_t)Vv*IDIM*2;  // 8,650,752
  const size_t off_pmax   = off_plab   + (size_t)Nn*Tt*LS*4;
  const size_t off_psum   = off_pmax   + (size_t)64*16384*4;
  const size_t off_lse    = off_psum   + (size_t)64*16384*4;
  const size_t off_labmap = off_lse    + (size_t)16384*4;
  const size_t off_extidx = off_labmap + (size_t)Nn*Vv*4;
  const size_t off_skip   = off_extidx + (size_t)((Nn*Ll*4 + 255) & ~255);

  bfu16* hsb    = (bfu16*)(ws + off_hsb);
  bfu16* Wb     = (bfu16*)(ws + off_Wb);
  float* plab   = (float*)(ws + off_plab);
  float* pmax   = (float*)(ws + off_pmax);
  float* psum   = (float*)(ws + off_psum);
  float* lse    = (float*)(ws + off_lse);
  int*   labmap = (int*)(ws + off_labmap);
  int*   extidx = (int*)(ws + off_extidx);
  int*   skipf  = (int*)(ws + off_skip);

  convert_zero<<<2048, 256, 0, stream>>>(
      (const float4*)hs, (const float4*)W, (ushort4*)hsb, (ushort4*)Wb, out);
  build_labels<<<16, 256, 0, stream>>>(ys, labmap, extidx, skipf);
  gemm_lse<<<dim3(128, 32), 256, 0, stream>>>(hsb, Wb, bias, labmap, plab, pmax, psum);
  lse_reduce<<<64, 256, 0, stream>>>(pmax, psum, lse);
  ctc_dp<<<16, 64, 0, stream>>>(plab, lse, extidx, skipf, hlens, ylens, out);
}

// Round 6
// 249.279 us; speedup vs baseline: 1.0041x; 1.0041x over previous
//
#include <hip/hip_runtime.h>
#include <cstdint>
#include <cstddef>

// ---------- types ----------
using short8_t = __attribute__((ext_vector_type(8))) short;
using f32x4    = __attribute__((ext_vector_type(4))) float;
typedef unsigned short bfu16;

constexpr int   Nn   = 16;
constexpr int   Tt   = 1024;
constexpr int   IDIM = 512;
constexpr int   Vv   = 4096;
constexpr int   Ss   = 128;
constexpr int   Ll   = 2 * Ss + 1;   // 257
constexpr int   LS   = 132;          // plab row stride (pad 129 -> 132)
constexpr float NEGV = -1e30f;
constexpr float L2E  = 1.4426950408889634f;  // log2(e)
constexpr float LN2  = 0.6931471805599453f;  // ln(2)

// ---------- helpers ----------
__device__ __forceinline__ float fexp2(float x) { return __builtin_amdgcn_exp2f(x); }
__device__ __forceinline__ float flog2(float x) { return __builtin_amdgcn_logf(x); }

__device__ __forceinline__ bfu16 f2bf(float f) {
  unsigned int x = __float_as_uint(f);
  x = x + 0x7fffu + ((x >> 16) & 1u);   // RNE (inputs are finite normals)
  return (bfu16)(x >> 16);
}

__device__ __forceinline__ void async16(const void* g, void* l) {
  __builtin_amdgcn_global_load_lds(
      (__attribute__((address_space(1))) void*)(g),
      (__attribute__((address_space(3))) void*)(l), 16, 0, 0);
}

// ---------- kernel 1: fp32 -> bf16 convert + zero output ----------
__global__ void convert_zero(const float4* __restrict__ hs4,
                             const float4* __restrict__ W4,
                             ushort4* __restrict__ hsb4,
                             ushort4* __restrict__ Wb4,
                             float* __restrict__ out) {
  if (blockIdx.x == 0 && threadIdx.x == 0) out[0] = 0.f;
  const int HS4 = (Nn * Tt * IDIM) / 4;        // 2097152
  const int TOT = HS4 + (Vv * IDIM) / 4;       // +524288
  for (int i = blockIdx.x * 256 + threadIdx.x; i < TOT; i += gridDim.x * 256) {
    float4 f;
    if (i < HS4) f = hs4[i]; else f = W4[i - HS4];
    ushort4 o;
    o.x = f2bf(f.x); o.y = f2bf(f.y); o.z = f2bf(f.z); o.w = f2bf(f.w);
    if (i < HS4) hsb4[i] = o; else Wb4[i - HS4] = o;
  }
}

// ---------- kernel 2: build label map / extended sequence ----------
__global__ void build_labels(const int* __restrict__ ys,
                             int* __restrict__ labmap,
                             int* __restrict__ extidx,
                             int* __restrict__ skipflag) {
  const int n = blockIdx.x, tid = threadIdx.x;
  int* lm = labmap + n * Vv;
  for (int v = tid; v < Vv; v += 256) lm[v] = 0x7fffffff;
  __syncthreads();
  if (tid == 0) lm[0] = 0;                                  // blank -> slot 0
  if (tid < Ss) atomicMin(&lm[ys[n * Ss + tid]], tid + 1);  // canonical = first occurrence
  __syncthreads();
  for (int s = tid; s < Ll; s += 256) {
    int v = (s & 1) ? ys[n * Ss + ((s - 1) >> 1)] : 0;
    extidx[n * Ll + s] = lm[v];
    int allow = 0;
    if ((s & 1) && s >= 3) allow = (v != ys[n * Ss + ((s - 3) >> 1)]) ? 1 : 0;
    skipflag[n * Ll + s] = allow;
  }
  __syncthreads();
  for (int v = tid; v < Vv; v += 256)
    if (lm[v] == 0x7fffffff) lm[v] = -1;
}

// ---------- kernel 3: bf16 MFMA GEMM fused with lse partials + label scatter ----------
// Triple-buffered LDS, stage-2-ahead, raw s_barrier + counted s_waitcnt vmcnt(4)
// (never drains to 0 in the loop). LDS chunk-XOR swizzle via pre-swizzled
// global source (global_load_lds writes linearly) + swizzled ds_read address.
__global__ __launch_bounds__(256) void gemm_lse(
    const bfu16* __restrict__ A,      // [16384][512] hs bf16
    const bfu16* __restrict__ B,      // [4096][512]  W  bf16 (B^T layout)
    const float* __restrict__ bias,   // [4096]
    const int*   __restrict__ labmap, // [16][4096]
    float* __restrict__ plab,         // [16384][LS]  exp2(logit*L2E) at label slots
    float* __restrict__ pmax,         // [64][16384]
    float* __restrict__ psum) {       // [64][16384]
  __shared__ bfu16 ldsA[3 * 128 * 32];    // 24 KB (triple-buffered)
  __shared__ bfu16 ldsB[3 * 128 * 32];    // 24 KB
  const int bR = blockIdx.x, bC = blockIdx.y;
  const int rowbase = bR * 128, colbase = bC * 128;
  const int tid  = threadIdx.x;
  const int lane = tid & 63, wid = tid >> 6;
  const int wr = wid >> 1, wc = wid & 1;

  f32x4 acc[4][4];
#pragma unroll
  for (int m = 0; m < 4; m++)
#pragma unroll
    for (int n = 0; n < 4; n++) {
      f32x4 z = {0.f, 0.f, 0.f, 0.f};
      acc[m][n] = z;
    }

  // ---- staging addresses (pre-swizzled source chunk) ----
  // lane l writes LDS row (wid*32 + (l>>2)) chunk (l&3); source chunk is
  // (l&3) ^ ((l>>3)&3) so that LDS(row,c) = global(row, c ^ ((row>>1)&3)).
  const int r16 = lane >> 2;                       // 0..15
  const int scb = (((lane & 3) ^ ((lane >> 3) & 3))) * 16;  // swizzled src chunk bytes
  const char* gA0 = (const char*)(A + (size_t)(rowbase + wid * 32 + r16) * IDIM) + scb;
  const char* gB0 = (const char*)(B + (size_t)(colbase + wid * 32 + r16) * IDIM) + scb;
  char* dA = (char*)ldsA + wid * 2048;
  char* dB = (char*)ldsB + wid * 2048;

  // ---- fragment-read addresses (swizzled chunk) ----
  const int fr  = lane & 15;
  const int rdB = (((lane >> 4) ^ ((fr >> 1) & 3))) * 16;   // swizzled chunk bytes

  // prefetch epilogue metadata early (latency hidden under K-loop)
  const int nsamp = bR >> 3;
  const int* lm = labmap + nsamp * Vv;
  float bc[4];
  int   slot[4];
#pragma unroll
  for (int n = 0; n < 4; n++) {
    int c = colbase + wc * 64 + n * 16 + fr;
    bc[n]   = bias[c];
    slot[n] = lm[c];
  }

  auto stage = [&](int bufoff, int k0) {
    const char* ga = gA0 + k0 * 2;
    const char* gb = gB0 + k0 * 2;
    char* da = dA + bufoff;
    char* db = dB + bufoff;
    async16(ga,         da);
    async16(ga + 16384, da + 1024);   // +16 rows (16*512*2 bytes)
    async16(gb,         db);
    async16(gb + 16384, db + 1024);
  };

  // prologue: tiles 0 and 1 in flight (each stage = 4 loads/wave)
  stage(0,    0);
  stage(8192, 32);

  int bufoff = 0;
  for (int it = 0; it < 16; ++it) {
    // wait: <=4 loads outstanding (the newest stage) => tile `it` resident.
    asm volatile("s_waitcnt vmcnt(4)" ::: "memory");
    __builtin_amdgcn_s_barrier();

    // stage tile it+2 (clamped: tail re-stages tile 15 into a dead buffer,
    // keeping the vmcnt arithmetic uniform). Buffer (it+2)%3 held tile it-1,
    // whose ds_reads were lgkm-drained by its MFMAs before this barrier.
    {
      int nb = bufoff + 16384; if (nb >= 24576) nb -= 24576;
      int kq = it + 2; if (kq > 15) kq = 15;
      stage(nb, kq * 32);
    }

    const char* lA = (const char*)ldsA + bufoff;
    const char* lB = (const char*)ldsB + bufoff;
    short8_t af[4], bfr[4];
#pragma unroll
    for (int m = 0; m < 4; m++)
      af[m] = *(const short8_t*)(lA + (wr * 64 + m * 16 + fr) * 64 + rdB);
#pragma unroll
    for (int n = 0; n < 4; n++)
      bfr[n] = *(const short8_t*)(lB + (wc * 64 + n * 16 + fr) * 64 + rdB);

#pragma unroll
    for (int m = 0; m < 4; m++)
#pragma unroll
      for (int n = 0; n < 4; n++)
        acc[m][n] = __builtin_amdgcn_mfma_f32_16x16x32_bf16(af[m], bfr[n], acc[m][n], 0, 0, 0);

    bufoff += 8192; if (bufoff == 24576) bufoff = 0;
  }

  // ---- epilogue: bias, label scatter (exp2'd), max-first lse partials ----
  const int g4 = (lane >> 4) * 4;

#pragma unroll
  for (int m = 0; m < 4; m++) {
#pragma unroll
    for (int r = 0; r < 4; r++) {
      int row = rowbase + wr * 64 + m * 16 + g4 + r;
      float v0 = acc[m][0][r] + bc[0];
      float v1 = acc[m][1][r] + bc[1];
      float v2 = acc[m][2][r] + bc[2];
      float v3 = acc[m][3][r] + bc[3];
      if (slot[0] >= 0) plab[(size_t)row * LS + slot[0]] = fexp2(v0 * L2E);
      if (slot[1] >= 0) plab[(size_t)row * LS + slot[1]] = fexp2(v1 * L2E);
      if (slot[2] >= 0) plab[(size_t)row * LS + slot[2]] = fexp2(v2 * L2E);
      if (slot[3] >= 0) plab[(size_t)row * LS + slot[3]] = fexp2(v3 * L2E);
      // max-first two-phase reduce across the 16-lane column group
      float mx = fmaxf(fmaxf(v0, v1), fmaxf(v2, v3));
#pragma unroll
      for (int off = 1; off < 16; off <<= 1)
        mx = fmaxf(mx, __shfl_xor(mx, off));
      float sm = fexp2((v0 - mx) * L2E) + fexp2((v1 - mx) * L2E) +
                 fexp2((v2 - mx) * L2E) + fexp2((v3 - mx) * L2E);
#pragma unroll
      for (int off = 1; off < 16; off <<= 1)
        sm += __shfl_xor(sm, off);
      if (fr == 0) {
        int pc = bC * 2 + wc;             // 0..63
        pmax[(size_t)pc * 16384 + row] = mx;
        psum[(size_t)pc * 16384 + row] = sm;
      }
    }
  }
}

// ---------- kernel 4: reduce 64 lse partials per row ----------
__global__ void lse_reduce(const float* __restrict__ pmax,
                           const float* __restrict__ psum,
                           float* __restrict__ lse) {
  int row = blockIdx.x * 256 + threadIdx.x;
  float m = NEGV, s = 0.f;
#pragma unroll 8
  for (int j = 0; j < 64; j++) {
    float pm = pmax[(size_t)j * 16384 + row];
    float ps = psum[(size_t)j * 16384 + row];
    float nm = fmaxf(m, pm);
    s = s * __expf(m - nm) + ps * __expf(pm - nm);
    m = nm;
  }
  lse[row] = m + __logf(s);
}

// ---------- kernel 5: CTC forward DP, one wave per sample ----------
// LINEAR-domain DP on raw-logit probabilities p = 2^(logit*L2E), with
// wave-uniform power-of-2 rescaling every 16 steps. Zero transcendentals
// in the serial loop. lse correction applied once at the end.
constexpr int DPD = 8;   // prefetch depth

__global__ __launch_bounds__(64) void ctc_dp(
    const float* __restrict__ plab, const float* __restrict__ lse,
    const int* __restrict__ extidx, const int* __restrict__ skipflag,
    const int* __restrict__ hlens, const int* __restrict__ ylens,
    float* __restrict__ out) {
  const int n    = blockIdx.x;
  const int lane = threadIdx.x;
  const int hlen = hlens[n];
  const int Ln   = 2 * ylens[n] + 1;
  const int sbase = lane * 4;   // states sbase..sbase+3; lane 63 also owns s=256

  // per-lane static DP metadata (even states are blanks since sbase is even)
  const int   e1  = extidx[n * Ll + sbase + 1];
  const int   e3  = extidx[n * Ll + sbase + 3];
  const float sk1 = skipflag[n * Ll + sbase + 1] ? 1.f : 0.f;
  const float sk3 = skipflag[n * Ll + sbase + 3] ? 1.f : 0.f;
  const float m0  = (sbase + 0 < Ln) ? 1.f : 0.f;
  const float m1  = (sbase + 1 < Ln) ? 1.f : 0.f;
  const float m2  = (sbase + 2 < Ln) ? 1.f : 0.f;
  const float m3  = (sbase + 3 < Ln) ? 1.f : 0.f;
  const float m4  = (lane == 63 && Ln == 257) ? 1.f : 0.f;

  const float* pl  = plab + (size_t)n * Tt * LS;
  const float* lsp = lse + n * Tt;

  // sum of lse over t < hlen (uniform across states -> applied once at end)
  float slse = 0.f;
  for (int t = lane; t < hlen; t += 64) slse += lsp[t];
#pragma unroll
  for (int off = 32; off; off >>= 1) slse += __shfl_xor(slse, off);

  // t = 0 init: alpha[0] = p_blank(0), alpha[1] = p_y1(0)
  float a0 = 0.f, a1 = 0.f, a2 = 0.f, a3 = 0.f, a4 = 0.f;
  if (lane == 0) { a0 = pl[0]; a1 = pl[e1]; }

  int sc = 0;   // accumulated log2 scale (true alpha = stored * 2^sc)

  auto step = [&](float pb, float p1, float p3) {
    float pm1 = __shfl_up(a3, 1);      // alpha[sbase-1]
    float pm2 = __shfl_up(a2, 1);      // alpha[sbase-2]
    pm1 = (lane == 0) ? 0.f : pm1;
    pm2 = (lane == 0) ? 0.f : pm2;
    float n4 = (a4 + a3) * pb * m4;                 // s=256 (blank), lane 63 only
    float n3 = (a3 + a2 + sk3 * a1)  * p3 * m3;     // odd (label)
    float n2 = (a2 + a1)             * pb * m2;     // even (blank)
    float n1 = (a1 + a0 + sk1 * pm2) * p1 * m1;     // odd (label)
    float n0 = (a0 + pm1)            * pb * m0;     // even (blank)
    a0 = n0; a1 = n1; a2 = n2; a3 = n3; a4 = n4;
  };

  auto rescale = [&]() {
    float mx = fmaxf(fmaxf(a0, a1), fmaxf(a2, a3));
    mx = fmaxf(mx, a4);
#pragma unroll
    for (int off = 32; off; off >>= 1) mx = fmaxf(mx, __shfl_xor(mx, off));
    int ee = (int)((__float_as_uint(mx) >> 23) & 0xff) - 127;   // floor(log2 mx)
    ee = (mx > 0.f) ? ee : 0;
    float s = __uint_as_float((unsigned)(127 - ee) << 23);      // 2^(-ee)
    sc += ee;
    a0 *= s; a1 *= s; a2 *= s; a3 *= s; a4 *= s;
  };

  // preload prefetch ring for t = 1..DPD (1 uniform blank + 2 gathers per row)
  float rb[DPD], r1[DPD], r3[DPD];
#pragma unroll
  for (int d = 0; d < DPD; d++) {
    int tt = 1 + d;
    rb[d] = pl[(size_t)tt * LS];
    r1[d] = pl[(size_t)tt * LS + e1];
    r3[d] = pl[(size_t)tt * LS + e3];
  }

  const int nfull = (hlen - 1) / DPD;
  for (int b = 0; b < nfull; b++) {
    const int t0 = 1 + b * DPD;
#pragma unroll
    for (int d = 0; d < DPD; d++) {
      float pb = rb[d], p1 = r1[d], p3 = r3[d];
      int tn = t0 + d + DPD;
      if (tn > Tt - 1) tn = Tt - 1;    // clamp keeps loads in-bounds
      rb[d] = pl[(size_t)tn * LS];
      r1[d] = pl[(size_t)tn * LS + e1];
      r3[d] = pl[(size_t)tn * LS + e3];
      step(pb, p1, p3);
    }
    if ((b & 1) || b == nfull - 1) rescale();   // every 16 steps + final block
  }
  // tail (< DPD steps): direct loads
  for (int t = 1 + nfull * DPD; t < hlen; t++) {
    step(pl[(size_t)t * LS], pl[(size_t)t * LS + e1], pl[(size_t)t * LS + e3]);
  }

  __shared__ float alf[264];
  alf[sbase + 0] = a0; alf[sbase + 1] = a1;
  alf[sbase + 2] = a2; alf[sbase + 3] = a3;
  if (lane == 63) alf[256] = a4;
  __syncthreads();
  if (lane == 0) {
    float sum = alf[Ln - 1] + alf[Ln - 2];
    float per = 0.f;
    if (sum > 0.f) {
      float llv = (flog2(sum) + (float)sc) * LN2 - slse;
      if (llv > -1e29f) per = -llv;
    }
    atomicAdd(out, per * (1.0f / 16.0f));
  }
}

// ---------- launcher ----------
extern "C" void kernel_launch(void* const* d_in, const int* in_sizes, int n_in,
                              void* d_out, int out_size, void* d_ws, size_t ws_size,
                              hipStream_t stream) {
  const float* hs    = (const float*)d_in[0];
  const int*   hlens = (const int*)d_in[1];
  const int*   ys    = (const int*)d_in[2];
  const int*   ylens = (const int*)d_in[3];
  const float* W     = (const float*)d_in[4];
  const float* bias  = (const float*)d_in[5];
  float*       out   = (float*)d_out;
  char*        ws    = (char*)d_ws;

  // workspace carve (bytes)
  const size_t off_hsb    = 0;                               // 16,777,216
  const size_t off_Wb     = off_hsb    + (size_t)Nn*Tt*IDIM*2;
  const size_t off_plab   = off_Wb     + (size_t)Vv*IDIM*2;  // 8,650,752
  const size_t off_pmax   = off_plab   + (size_t)Nn*Tt*LS*4;
  const size_t off_psum   = off_pmax   + (size_t)64*16384*4;
  const size_t off_lse    = off_psum   + (size_t)64*16384*4;
  const size_t off_labmap = off_lse    + (size_t)16384*4;
  const size_t off_extidx = off_labmap + (size_t)Nn*Vv*4;
  const size_t off_skip   = off_extidx + (size_t)((Nn*Ll*4 + 255) & ~255);

  bfu16* hsb    = (bfu16*)(ws + off_hsb);
  bfu16* Wb     = (bfu16*)(ws + off_Wb);
  float* plab   = (float*)(ws + off_plab);
  float* pmax   = (float*)(ws + off_pmax);
  float* psum   = (float*)(ws + off_psum);
  float* lse    = (float*)(ws + off_lse);
  int*   labmap = (int*)(ws + off_labmap);
  int*   extidx = (int*)(ws + off_extidx);
  int*   skipf  = (int*)(ws + off_skip);

  convert_zero<<<2048, 256, 0, stream>>>(
      (const float4*)hs, (const float4*)W, (ushort4*)hsb, (ushort4*)Wb, out);
  build_labels<<<16, 256, 0, stream>>>(ys, labmap, extidx, skipf);
  gemm_lse<<<dim3(128, 32), 256, 0, stream>>>(hsb, Wb, bias, labmap, plab, pmax, psum);
  lse_reduce<<<64, 256, 0, stream>>>(pmax, psum, lse);
  ctc_dp<<<16, 64, 0, stream>>>(plab, lse, extidx, skipf, hlens, ylens, out);
}

// Round 7
// 238.138 us; speedup vs baseline: 1.0511x; 1.0468x over previous
//
#include <hip/hip_runtime.h>
#include <cstdint>
#include <cstddef>

// ---------- types ----------
using short8_t = __attribute__((ext_vector_type(8))) short;
using f32x4    = __attribute__((ext_vector_type(4))) float;
typedef unsigned short bfu16;

constexpr int   Nn   = 16;
constexpr int   Tt   = 1024;
constexpr int   IDIM = 512;
constexpr int   Vv   = 4096;
constexpr int   Ss   = 128;
constexpr int   Ll   = 2 * Ss + 1;   // 257
constexpr int   LS   = 132;          // plab row stride (pad 129 -> 132)
constexpr float NEGV = -1e30f;
constexpr float L2E  = 1.4426950408889634f;  // log2(e)
constexpr float LN2  = 0.6931471805599453f;  // ln(2)

// ---------- helpers ----------
__device__ __forceinline__ float fexp2(float x) { return __builtin_amdgcn_exp2f(x); }
__device__ __forceinline__ float flog2(float x) { return __builtin_amdgcn_logf(x); }

__device__ __forceinline__ bfu16 f2bf(float f) {
  unsigned int x = __float_as_uint(f);
  x = x + 0x7fffu + ((x >> 16) & 1u);   // RNE (inputs are finite normals)
  return (bfu16)(x >> 16);
}

__device__ __forceinline__ void async16(const void* g, void* l) {
  __builtin_amdgcn_global_load_lds(
      (__attribute__((address_space(1))) void*)(g),
      (__attribute__((address_space(3))) void*)(l), 16, 0, 0);
}

// ---------- kernel 1: fp32 -> bf16 convert + zero output ----------
__global__ void convert_zero(const float4* __restrict__ hs4,
                             const float4* __restrict__ W4,
                             ushort4* __restrict__ hsb4,
                             ushort4* __restrict__ Wb4,
                             float* __restrict__ out) {
  if (blockIdx.x == 0 && threadIdx.x == 0) out[0] = 0.f;
  const int HS4 = (Nn * Tt * IDIM) / 4;        // 2097152
  const int TOT = HS4 + (Vv * IDIM) / 4;       // +524288
  for (int i = blockIdx.x * 256 + threadIdx.x; i < TOT; i += gridDim.x * 256) {
    float4 f;
    if (i < HS4) f = hs4[i]; else f = W4[i - HS4];
    ushort4 o;
    o.x = f2bf(f.x); o.y = f2bf(f.y); o.z = f2bf(f.z); o.w = f2bf(f.w);
    if (i < HS4) hsb4[i] = o; else Wb4[i - HS4] = o;
  }
}

// ---------- kernel 2: build label map / extended sequence ----------
__global__ void build_labels(const int* __restrict__ ys,
                             int* __restrict__ labmap,
                             int* __restrict__ extidx,
                             int* __restrict__ skipflag) {
  const int n = blockIdx.x, tid = threadIdx.x;
  int* lm = labmap + n * Vv;
  for (int v = tid; v < Vv; v += 256) lm[v] = 0x7fffffff;
  __syncthreads();
  if (tid == 0) lm[0] = 0;                                  // blank -> slot 0
  if (tid < Ss) atomicMin(&lm[ys[n * Ss + tid]], tid + 1);  // canonical = first occurrence
  __syncthreads();
  for (int s = tid; s < Ll; s += 256) {
    int v = (s & 1) ? ys[n * Ss + ((s - 1) >> 1)] : 0;
    extidx[n * Ll + s] = lm[v];
    int allow = 0;
    if ((s & 1) && s >= 3) allow = (v != ys[n * Ss + ((s - 3) >> 1)]) ? 1 : 0;
    skipflag[n * Ll + s] = allow;
  }
  __syncthreads();
  for (int v = tid; v < Vv; v += 256)
    if (lm[v] == 0x7fffffff) lm[v] = -1;
}

// ---------- kernel 3: 256x256 BK=64 8-wave MFMA GEMM fused with lse + label scatter ----
// Wave tile 128x64 (acc[8][4] of 16x16), 43.7 FLOP/LDS-byte.
// LDS: 2 buf x (A 32KB + B 32KB) = 128KB, 1 block/CU.
// Per K-tile: phase kk0 {stage next tile (8 gload_lds), 12 ds_read, 32 MFMA, barrier}
//             phase kk1 {12 ds_read, 32 MFMA, vmcnt(0), barrier}.
// Chunk-XOR swizzle for 128B LDS rows: LDS(row,c) = global(row, c ^ (row&7)),
// applied via pre-swizzled global source + swizzled ds_read chunk.
__global__ __launch_bounds__(512, 2) void gemm_lse(
    const bfu16* __restrict__ A,      // [16384][512] hs bf16
    const bfu16* __restrict__ B,      // [4096][512]  W  bf16 (B^T layout)
    const float* __restrict__ bias,   // [4096]
    const int*   __restrict__ labmap, // [16][4096]
    float* __restrict__ plab,         // [16384][LS]  exp2(logit*L2E) at label slots
    float* __restrict__ pmax,         // [64][16384]
    float* __restrict__ psum) {       // [64][16384]
  __shared__ alignas(128) char ldsraw[131072];   // [buf][A/B][32KB]
  const int tid  = threadIdx.x;
  const int lane = tid & 63, wid = tid >> 6;     // 8 waves
  const int wr = wid >> 2, wc = wid & 3;         // 2M x 4N wave grid

  // bijective XCD swizzle (1024 % 8 == 0): XCD k gets contiguous wg chunk
  const int flat = blockIdx.x;
  const int wg   = (flat & 7) * 128 + (flat >> 3);
  const int bR = wg >> 4, bC = wg & 15;
  const int rowbase = bR * 256, colbase = bC * 256;

  f32x4 acc[8][4];
#pragma unroll
  for (int m = 0; m < 8; m++)
#pragma unroll
    for (int n = 0; n < 4; n++) {
      f32x4 z = {0.f, 0.f, 0.f, 0.f};
      acc[m][n] = z;
    }

  // ---- staging setup: waves 0-3 stage A (64 rows each), 4-7 stage B ----
  const int  sw  = wid & 3;
  const bool isB = wid >= 4;
  const char* gsrc0 = (const char*)(isB ? (const void*)B : (const void*)A)
      + (size_t)((isB ? colbase : rowbase) + sw * 64 + (lane >> 3)) * (IDIM * 2)
      + (((lane & 7) ^ ((lane >> 3) & 7)) * 16);     // pre-swizzled source chunk
  char* ldst0 = ldsraw + (isB ? 32768 : 0) + sw * 8192;

  // ---- fragment-read setup ----
  const int fr = lane & 15;          // fragment row (A row / B col low bits)
  const int g  = lane >> 4;          // k-chunk 0..3 within K=32 half
  const int fx = fr & 7;             // row&7 for the XOR swizzle

  // epilogue metadata (prefetched; latency hidden under K-loop)
  const int nsamp = bR >> 2;         // 4 row-blocks (256) per sample (1024)
  const int* lm = labmap + nsamp * Vv;
  float bc[4];
  int   slot[4];
#pragma unroll
  for (int n = 0; n < 4; n++) {
    int c = colbase + wc * 64 + n * 16 + fr;
    bc[n]   = bias[c];
    slot[n] = lm[c];
  }

  auto stage = [&](int b, int t) {
#pragma unroll
    for (int i = 0; i < 8; ++i)
      async16(gsrc0 + (size_t)t * 128 + i * 8192, ldst0 + b * 65536 + i * 1024);
  };

  // prologue: tile 0 into buf 0
  stage(0, 0);
  asm volatile("s_waitcnt vmcnt(0)" ::: "memory");
  __builtin_amdgcn_s_barrier();

  int buf = 0;
  for (int t = 0; t < 8; ++t) {
    const char* Ab = ldsraw + buf * 65536;
    const char* Bb = Ab + 32768;

    // ---- phase kk = 0 ----
    if (t < 7) stage(buf ^ 1, t + 1);     // issue early: ~2 phases of cover
    {
      short8_t af[8], bfr[4];
#pragma unroll
      for (int m = 0; m < 8; m++)
        af[m] = *(const short8_t*)(Ab + (wr * 128 + m * 16 + fr) * 128 + ((0 + g) ^ fx) * 16);
#pragma unroll
      for (int n = 0; n < 4; n++)
        bfr[n] = *(const short8_t*)(Bb + (wc * 64 + n * 16 + fr) * 128 + ((0 + g) ^ fx) * 16);
      __builtin_amdgcn_s_setprio(1);
#pragma unroll
      for (int m = 0; m < 8; m++)
#pragma unroll
        for (int n = 0; n < 4; n++)
          acc[m][n] = __builtin_amdgcn_mfma_f32_16x16x32_bf16(af[m], bfr[n], acc[m][n], 0, 0, 0);
      __builtin_amdgcn_s_setprio(0);
    }
    __builtin_amdgcn_s_barrier();

    // ---- phase kk = 1 ----
    {
      short8_t af[8], bfr[4];
#pragma unroll
      for (int m = 0; m < 8; m++)
        af[m] = *(const short8_t*)(Ab + (wr * 128 + m * 16 + fr) * 128 + ((4 + g) ^ fx) * 16);
#pragma unroll
      for (int n = 0; n < 4; n++)
        bfr[n] = *(const short8_t*)(Bb + (wc * 64 + n * 16 + fr) * 128 + ((4 + g) ^ fx) * 16);
      __builtin_amdgcn_s_setprio(1);
#pragma unroll
      for (int m = 0; m < 8; m++)
#pragma unroll
        for (int n = 0; n < 4; n++)
          acc[m][n] = __builtin_amdgcn_mfma_f32_16x16x32_bf16(af[m], bfr[n], acc[m][n], 0, 0, 0);
      __builtin_amdgcn_s_setprio(0);
    }
    // boundary: next tile's loads (issued at this tile's phase-0 start) done
    asm volatile("s_waitcnt vmcnt(0)" ::: "memory");
    __builtin_amdgcn_s_barrier();
    buf ^= 1;
  }

  // ---- epilogue: bias, label scatter (exp2'd), max-first lse partials ----
  const int g4 = g * 4;
#pragma unroll
  for (int m = 0; m < 8; m++) {
#pragma unroll
    for (int r = 0; r < 4; r++) {
      int row = rowbase + wr * 128 + m * 16 + g4 + r;
      float v0 = acc[m][0][r] + bc[0];
      float v1 = acc[m][1][r] + bc[1];
      float v2 = acc[m][2][r] + bc[2];
      float v3 = acc[m][3][r] + bc[3];
      if (slot[0] >= 0) plab[(size_t)row * LS + slot[0]] = fexp2(v0 * L2E);
      if (slot[1] >= 0) plab[(size_t)row * LS + slot[1]] = fexp2(v1 * L2E);
      if (slot[2] >= 0) plab[(size_t)row * LS + slot[2]] = fexp2(v2 * L2E);
      if (slot[3] >= 0) plab[(size_t)row * LS + slot[3]] = fexp2(v3 * L2E);
      float mx = fmaxf(fmaxf(v0, v1), fmaxf(v2, v3));
#pragma unroll
      for (int off = 1; off < 16; off <<= 1)
        mx = fmaxf(mx, __shfl_xor(mx, off));
      float sm = fexp2((v0 - mx) * L2E) + fexp2((v1 - mx) * L2E) +
                 fexp2((v2 - mx) * L2E) + fexp2((v3 - mx) * L2E);
#pragma unroll
      for (int off = 1; off < 16; off <<= 1)
        sm += __shfl_xor(sm, off);
      if (fr == 0) {
        int pc = bC * 4 + wc;             // 0..63
        pmax[(size_t)pc * 16384 + row] = mx;
        psum[(size_t)pc * 16384 + row] = sm;
      }
    }
  }
}

// ---------- kernel 4: reduce 64 lse partials per row ----------
__global__ void lse_reduce(const float* __restrict__ pmax,
                           const float* __restrict__ psum,
                           float* __restrict__ lse) {
  int row = blockIdx.x * 256 + threadIdx.x;
  float m = NEGV, s = 0.f;
#pragma unroll 8
  for (int j = 0; j < 64; j++) {
    float pm = pmax[(size_t)j * 16384 + row];
    float ps = psum[(size_t)j * 16384 + row];
    float nm = fmaxf(m, pm);
    s = s * __expf(m - nm) + ps * __expf(pm - nm);
    m = nm;
  }
  lse[row] = m + __logf(s);
}

// ---------- kernel 5: CTC forward DP, one wave per sample ----------
// LINEAR-domain DP on raw-logit probabilities p = 2^(logit*L2E), with
// wave-uniform power-of-2 rescaling every 16 steps. Zero transcendentals
// in the serial loop. lse correction applied once at the end.
constexpr int DPD = 8;   // prefetch depth

__global__ __launch_bounds__(64) void ctc_dp(
    const float* __restrict__ plab, const float* __restrict__ lse,
    const int* __restrict__ extidx, const int* __restrict__ skipflag,
    const int* __restrict__ hlens, const int* __restrict__ ylens,
    float* __restrict__ out) {
  const int n    = blockIdx.x;
  const int lane = threadIdx.x;
  const int hlen = hlens[n];
  const int Ln   = 2 * ylens[n] + 1;
  const int sbase = lane * 4;   // states sbase..sbase+3; lane 63 also owns s=256

  // per-lane static DP metadata (even states are blanks since sbase is even)
  const int   e1  = extidx[n * Ll + sbase + 1];
  const int   e3  = extidx[n * Ll + sbase + 3];
  const float sk1 = skipflag[n * Ll + sbase + 1] ? 1.f : 0.f;
  const float sk3 = skipflag[n * Ll + sbase + 3] ? 1.f : 0.f;
  const float m0  = (sbase + 0 < Ln) ? 1.f : 0.f;
  const float m1  = (sbase + 1 < Ln) ? 1.f : 0.f;
  const float m2  = (sbase + 2 < Ln) ? 1.f : 0.f;
  const float m3  = (sbase + 3 < Ln) ? 1.f : 0.f;
  const float m4  = (lane == 63 && Ln == 257) ? 1.f : 0.f;

  const float* pl  = plab + (size_t)n * Tt * LS;
  const float* lsp = lse + n * Tt;

  // sum of lse over t < hlen (uniform across states -> applied once at end)
  float slse = 0.f;
  for (int t = lane; t < hlen; t += 64) slse += lsp[t];
#pragma unroll
  for (int off = 32; off; off >>= 1) slse += __shfl_xor(slse, off);

  // t = 0 init: alpha[0] = p_blank(0), alpha[1] = p_y1(0)
  float a0 = 0.f, a1 = 0.f, a2 = 0.f, a3 = 0.f, a4 = 0.f;
  if (lane == 0) { a0 = pl[0]; a1 = pl[e1]; }

  int sc = 0;   // accumulated log2 scale (true alpha = stored * 2^sc)

  auto step = [&](float pb, float p1, float p3) {
    float pm1 = __shfl_up(a3, 1);      // alpha[sbase-1]
    float pm2 = __shfl_up(a2, 1);      // alpha[sbase-2]
    pm1 = (lane == 0) ? 0.f : pm1;
    pm2 = (lane == 0) ? 0.f : pm2;
    float n4 = (a4 + a3) * pb * m4;                 // s=256 (blank), lane 63 only
    float n3 = (a3 + a2 + sk3 * a1)  * p3 * m3;     // odd (label)
    float n2 = (a2 + a1)             * pb * m2;     // even (blank)
    float n1 = (a1 + a0 + sk1 * pm2) * p1 * m1;     // odd (label)
    float n0 = (a0 + pm1)            * pb * m0;     // even (blank)
    a0 = n0; a1 = n1; a2 = n2; a3 = n3; a4 = n4;
  };

  auto rescale = [&]() {
    float mx = fmaxf(fmaxf(a0, a1), fmaxf(a2, a3));
    mx = fmaxf(mx, a4);
#pragma unroll
    for (int off = 32; off; off >>= 1) mx = fmaxf(mx, __shfl_xor(mx, off));
    int ee = (int)((__float_as_uint(mx) >> 23) & 0xff) - 127;   // floor(log2 mx)
    ee = (mx > 0.f) ? ee : 0;
    float s = __uint_as_float((unsigned)(127 - ee) << 23);      // 2^(-ee)
    sc += ee;
    a0 *= s; a1 *= s; a2 *= s; a3 *= s; a4 *= s;
  };

  // preload prefetch ring for t = 1..DPD (1 uniform blank + 2 gathers per row)
  float rb[DPD], r1[DPD], r3[DPD];
#pragma unroll
  for (int d = 0; d < DPD; d++) {
    int tt = 1 + d;
    rb[d] = pl[(size_t)tt * LS];
    r1[d] = pl[(size_t)tt * LS + e1];
    r3[d] = pl[(size_t)tt * LS + e3];
  }

  const int nfull = (hlen - 1) / DPD;
  for (int b = 0; b < nfull; b++) {
    const int t0 = 1 + b * DPD;
#pragma unroll
    for (int d = 0; d < DPD; d++) {
      float pb = rb[d], p1 = r1[d], p3 = r3[d];
      int tn = t0 + d + DPD;
      if (tn > Tt - 1) tn = Tt - 1;    // clamp keeps loads in-bounds
      rb[d] = pl[(size_t)tn * LS];
      r1[d] = pl[(size_t)tn * LS + e1];
      r3[d] = pl[(size_t)tn * LS + e3];
      step(pb, p1, p3);
    }
    if ((b & 1) || b == nfull - 1) rescale();   // every 16 steps + final block
  }
  // tail (< DPD steps): direct loads
  for (int t = 1 + nfull * DPD; t < hlen; t++) {
    step(pl[(size_t)t * LS], pl[(size_t)t * LS + e1], pl[(size_t)t * LS + e3]);
  }

  __shared__ float alf[264];
  alf[sbase + 0] = a0; alf[sbase + 1] = a1;
  alf[sbase + 2] = a2; alf[sbase + 3] = a3;
  if (lane == 63) alf[256] = a4;
  __syncthreads();
  if (lane == 0) {
    float sum = alf[Ln - 1] + alf[Ln - 2];
    float per = 0.f;
    if (sum > 0.f) {
      float llv = (flog2(sum) + (float)sc) * LN2 - slse;
      if (llv > -1e29f) per = -llv;
    }
    atomicAdd(out, per * (1.0f / 16.0f));
  }
}

// ---------- launcher ----------
extern "C" void kernel_launch(void* const* d_in, const int* in_sizes, int n_in,
                              void* d_out, int out_size, void* d_ws, size_t ws_size,
                              hipStream_t stream) {
  const float* hs    = (const float*)d_in[0];
  const int*   hlens = (const int*)d_in[1];
  const int*   ys    = (const int*)d_in[2];
  const int*   ylens = (const int*)d_in[3];
  const float* W     = (const float*)d_in[4];
  const float* bias  = (const float*)d_in[5];
  float*       out   = (float*)d_out;
  char*        ws    = (char*)d_ws;

  // workspace carve (bytes)
  const size_t off_hsb    = 0;                               // 16,777,216
  const size_t off_Wb     = off_hsb    + (size_t)Nn*Tt*IDIM*2;
  const size_t off_plab   = off_Wb     + (size_t)Vv*IDIM*2;  // 8,650,752
  const size_t off_pmax   = off_plab   + (size_t)Nn*Tt*LS*4;
  const size_t off_psum   = off_pmax   + (size_t)64*16384*4;
  const size_t off_lse    = off_psum   + (size_t)64*16384*4;
  const size_t off_labmap = off_lse    + (size_t)16384*4;
  const size_t off_extidx = off_labmap + (size_t)Nn*Vv*4;
  const size_t off_skip   = off_extidx + (size_t)((Nn*Ll*4 + 255) & ~255);

  bfu16* hsb    = (bfu16*)(ws + off_hsb);
  bfu16* Wb     = (bfu16*)(ws + off_Wb);
  float* plab   = (float*)(ws + off_plab);
  float* pmax   = (float*)(ws + off_pmax);
  float* psum   = (float*)(ws + off_psum);
  float* lse    = (float*)(ws + off_lse);
  int*   labmap = (int*)(ws + off_labmap);
  int*   extidx = (int*)(ws + off_extidx);
  int*   skipf  = (int*)(ws + off_skip);

  convert_zero<<<2048, 256, 0, stream>>>(
      (const float4*)hs, (const float4*)W, (ushort4*)hsb, (ushort4*)Wb, out);
  build_labels<<<16, 256, 0, stream>>>(ys, labmap, extidx, skipf);
  gemm_lse<<<1024, 512, 0, stream>>>(hsb, Wb, bias, labmap, plab, pmax, psum);
  lse_reduce<<<64, 256, 0, stream>>>(pmax, psum, lse);
  ctc_dp<<<16, 64, 0, stream>>>(plab, lse, extidx, skipf, hlens, ylens, out);
}

// Round 8
// 211.071 us; speedup vs baseline: 1.1859x; 1.1282x over previous
//
#include <hip/hip_runtime.h>
#include <cstdint>
#include <cstddef>

// ---------- types ----------
using short8_t = __attribute__((ext_vector_type(8))) short;
using f32x4    = __attribute__((ext_vector_type(4))) float;
typedef unsigned short bfu16;

constexpr int   Nn   = 16;
constexpr int   Tt   = 1024;
constexpr int   IDIM = 512;
constexpr int   Vv   = 4096;
constexpr int   Ss   = 128;
constexpr int   Ll   = 2 * Ss + 1;   // 257
constexpr int   LS   = 132;          // plab row stride (pad 129 -> 132)
constexpr float NEGV = -1e30f;
constexpr float L2E  = 1.4426950408889634f;  // log2(e)
constexpr float LN2  = 0.6931471805599453f;  // ln(2)

// ---------- helpers ----------
__device__ __forceinline__ float fexp2(float x) { return __builtin_amdgcn_exp2f(x); }
__device__ __forceinline__ float flog2(float x) { return __builtin_amdgcn_logf(x); }

__device__ __forceinline__ bfu16 f2bf(float f) {
  unsigned int x = __float_as_uint(f);
  x = x + 0x7fffu + ((x >> 16) & 1u);   // RNE (inputs are finite normals)
  return (bfu16)(x >> 16);
}

__device__ __forceinline__ void async16(const void* g, void* l) {
  __builtin_amdgcn_global_load_lds(
      (__attribute__((address_space(1))) void*)(g),
      (__attribute__((address_space(3))) void*)(l), 16, 0, 0);
}

// ---------- kernel 1: fp32 -> bf16 convert + zero output ----------
__global__ void convert_zero(const float4* __restrict__ hs4,
                             const float4* __restrict__ W4,
                             ushort4* __restrict__ hsb4,
                             ushort4* __restrict__ Wb4,
                             float* __restrict__ out) {
  if (blockIdx.x == 0 && threadIdx.x == 0) out[0] = 0.f;
  const int HS4 = (Nn * Tt * IDIM) / 4;        // 2097152
  const int TOT = HS4 + (Vv * IDIM) / 4;       // +524288
  for (int i = blockIdx.x * 256 + threadIdx.x; i < TOT; i += gridDim.x * 256) {
    float4 f;
    if (i < HS4) f = hs4[i]; else f = W4[i - HS4];
    ushort4 o;
    o.x = f2bf(f.x); o.y = f2bf(f.y); o.z = f2bf(f.z); o.w = f2bf(f.w);
    if (i < HS4) hsb4[i] = o; else Wb4[i - HS4] = o;
  }
}

// ---------- kernel 2: build label map / extended sequence ----------
__global__ void build_labels(const int* __restrict__ ys,
                             int* __restrict__ labmap,
                             int* __restrict__ extidx,
                             int* __restrict__ skipflag) {
  const int n = blockIdx.x, tid = threadIdx.x;
  int* lm = labmap + n * Vv;
  for (int v = tid; v < Vv; v += 256) lm[v] = 0x7fffffff;
  __syncthreads();
  if (tid == 0) lm[0] = 0;                                  // blank -> slot 0
  if (tid < Ss) atomicMin(&lm[ys[n * Ss + tid]], tid + 1);  // canonical = first occurrence
  __syncthreads();
  for (int s = tid; s < Ll; s += 256) {
    int v = (s & 1) ? ys[n * Ss + ((s - 1) >> 1)] : 0;
    extidx[n * Ll + s] = lm[v];
    int allow = 0;
    if ((s & 1) && s >= 3) allow = (v != ys[n * Ss + ((s - 3) >> 1)]) ? 1 : 0;
    skipflag[n * Ll + s] = allow;
  }
  __syncthreads();
  for (int v = tid; v < Vv; v += 256)
    if (lm[v] == 0x7fffffff) lm[v] = -1;
}

// ---------- kernel 3: 256x256 BK=64 8-wave MFMA GEMM fused with lse + label scatter ----
// Quadrant-pipelined K-loop: 4 phases of 16 MFMA per K-tile, ds_reads issued one
// quadrant ahead, NO mid-tile barriers (LDS read-only within a tile), single
// vmcnt(0)+s_barrier per tile. Chunk-XOR swizzle (c ^= row&7) via pre-swizzled
// global source + swizzled ds_read chunk (0 bank conflicts, verified R7).
__global__ __launch_bounds__(512, 2) void gemm_lse(
    const bfu16* __restrict__ A,      // [16384][512] hs bf16
    const bfu16* __restrict__ B,      // [4096][512]  W  bf16 (B^T layout)
    const float* __restrict__ bias,   // [4096]
    const int*   __restrict__ labmap, // [16][4096]
    float* __restrict__ plab,         // [16384][LS]  exp2(logit*L2E) at label slots
    float* __restrict__ psum) {       // [64][16384]  sum of exp2(logit*L2E) partials
  __shared__ alignas(128) char ldsraw[131072];   // [buf][A/B][32KB]
  const int tid  = threadIdx.x;
  const int lane = tid & 63, wid = tid >> 6;     // 8 waves
  const int wr = wid >> 2, wc = wid & 3;         // 2M x 4N wave grid

  // bijective XCD swizzle (1024 % 8 == 0)
  const int flat = blockIdx.x;
  const int wg   = (flat & 7) * 128 + (flat >> 3);
  const int bR = wg >> 4, bC = wg & 15;
  const int rowbase = bR * 256, colbase = bC * 256;

  f32x4 acc[8][4];
#pragma unroll
  for (int m = 0; m < 8; m++)
#pragma unroll
    for (int n = 0; n < 4; n++) {
      f32x4 z = {0.f, 0.f, 0.f, 0.f};
      acc[m][n] = z;
    }

  // ---- staging setup: waves 0-3 stage A (64 rows each), 4-7 stage B ----
  const int  sw  = wid & 3;
  const bool isB = wid >= 4;
  const char* gsrc0 = (const char*)(isB ? (const void*)B : (const void*)A)
      + (size_t)((isB ? colbase : rowbase) + sw * 64 + (lane >> 3)) * (IDIM * 2)
      + (((lane & 7) ^ ((lane >> 3) & 7)) * 16);     // pre-swizzled source chunk
  char* ldst0 = ldsraw + (isB ? 32768 : 0) + sw * 8192;

  // ---- fragment-read setup ----
  const int fr = lane & 15;          // fragment row (A row / B col low bits)
  const int g  = lane >> 4;          // k-chunk 0..3 within K=32 half
  const int fx = fr & 7;             // row&7 for the XOR swizzle

  // epilogue metadata (prefetched; latency hidden under K-loop)
  const int nsamp = bR >> 2;         // 4 row-blocks (256) per sample (1024)
  const int* lm = labmap + nsamp * Vv;
  float bc[4];
  int   slot[4];
#pragma unroll
  for (int n = 0; n < 4; n++) {
    int c = colbase + wc * 64 + n * 16 + fr;
    bc[n]   = bias[c];
    slot[n] = lm[c];
  }

  auto stage = [&](int b, int t) {
#pragma unroll
    for (int i = 0; i < 8; ++i)
      async16(gsrc0 + (size_t)t * 128 + i * 8192, ldst0 + b * 65536 + i * 1024);
  };

  // prologue: tile 0 into buf 0
  stage(0, 0);
  asm volatile("s_waitcnt vmcnt(0)" ::: "memory");
  __builtin_amdgcn_s_barrier();

  int buf = 0;
  for (int t = 0; t < 8; ++t) {
    const char* Ab = ldsraw + buf * 65536;
    const char* Bb = Ab + 32768;
    if (t < 7) stage(buf ^ 1, t + 1);   // issue early: full tile of cover

    // quadrant-pipelined schedule
    short8_t a0[4], a1[4], a2[4], a3[4], b0[4], b1[4];
    // Q0 reads (A mh0 ks0 + B ks0)
#pragma unroll
    for (int m = 0; m < 4; m++)
      a0[m] = *(const short8_t*)(Ab + (wr * 128 + m * 16 + fr) * 128 + ((0 + g) ^ fx) * 16);
#pragma unroll
    for (int n = 0; n < 4; n++)
      b0[n] = *(const short8_t*)(Bb + (wc * 64 + n * 16 + fr) * 128 + ((0 + g) ^ fx) * 16);
    // Q1 reads (A mh1 ks0)
#pragma unroll
    for (int m = 0; m < 4; m++)
      a1[m] = *(const short8_t*)(Ab + (wr * 128 + (m + 4) * 16 + fr) * 128 + ((0 + g) ^ fx) * 16);

    // MFMA Q0
    __builtin_amdgcn_s_setprio(1);
#pragma unroll
    for (int m = 0; m < 4; m++)
#pragma unroll
      for (int n = 0; n < 4; n++)
        acc[m][n] = __builtin_amdgcn_mfma_f32_16x16x32_bf16(a0[m], b0[n], acc[m][n], 0, 0, 0);
    __builtin_amdgcn_s_setprio(0);

    // Q2 reads (A mh0 ks1 + B ks1)
#pragma unroll
    for (int m = 0; m < 4; m++)
      a2[m] = *(const short8_t*)(Ab + (wr * 128 + m * 16 + fr) * 128 + ((4 + g) ^ fx) * 16);
#pragma unroll
    for (int n = 0; n < 4; n++)
      b1[n] = *(const short8_t*)(Bb + (wc * 64 + n * 16 + fr) * 128 + ((4 + g) ^ fx) * 16);

    // MFMA Q1
    __builtin_amdgcn_s_setprio(1);
#pragma unroll
    for (int m = 0; m < 4; m++)
#pragma unroll
      for (int n = 0; n < 4; n++)
        acc[m + 4][n] = __builtin_amdgcn_mfma_f32_16x16x32_bf16(a1[m], b0[n], acc[m + 4][n], 0, 0, 0);
    __builtin_amdgcn_s_setprio(0);

    // Q3 reads (A mh1 ks1)
#pragma unroll
    for (int m = 0; m < 4; m++)
      a3[m] = *(const short8_t*)(Ab + (wr * 128 + (m + 4) * 16 + fr) * 128 + ((4 + g) ^ fx) * 16);

    // MFMA Q2
    __builtin_amdgcn_s_setprio(1);
#pragma unroll
    for (int m = 0; m < 4; m++)
#pragma unroll
      for (int n = 0; n < 4; n++)
        acc[m][n] = __builtin_amdgcn_mfma_f32_16x16x32_bf16(a2[m], b1[n], acc[m][n], 0, 0, 0);
    __builtin_amdgcn_s_setprio(0);

    // MFMA Q3
    __builtin_amdgcn_s_setprio(1);
#pragma unroll
    for (int m = 0; m < 4; m++)
#pragma unroll
      for (int n = 0; n < 4; n++)
        acc[m + 4][n] = __builtin_amdgcn_mfma_f32_16x16x32_bf16(a3[m], b1[n], acc[m + 4][n], 0, 0, 0);
    __builtin_amdgcn_s_setprio(0);

    asm volatile("s_waitcnt vmcnt(0)" ::: "memory");   // next tile resident
    __builtin_amdgcn_s_barrier();
    buf ^= 1;
  }

  // ---- epilogue: bias, label scatter (exp2'd), max-free sumexp2 partials ----
  // (logits for this problem are bounded |v| < ~10; exp2 sums fit fp32 easily)
  const int g4 = g * 4;
#pragma unroll
  for (int m = 0; m < 8; m++) {
#pragma unroll
    for (int r = 0; r < 4; r++) {
      int row = rowbase + wr * 128 + m * 16 + g4 + r;
      float e0 = fexp2((acc[m][0][r] + bc[0]) * L2E);
      float e1 = fexp2((acc[m][1][r] + bc[1]) * L2E);
      float e2 = fexp2((acc[m][2][r] + bc[2]) * L2E);
      float e3 = fexp2((acc[m][3][r] + bc[3]) * L2E);
      if (slot[0] >= 0) plab[(size_t)row * LS + slot[0]] = e0;
      if (slot[1] >= 0) plab[(size_t)row * LS + slot[1]] = e1;
      if (slot[2] >= 0) plab[(size_t)row * LS + slot[2]] = e2;
      if (slot[3] >= 0) plab[(size_t)row * LS + slot[3]] = e3;
      float s = (e0 + e1) + (e2 + e3);
      s += __shfl_xor(s, 1);
      s += __shfl_xor(s, 2);
      s += __shfl_xor(s, 4);
      s += __shfl_xor(s, 8);
      if (fr == 0) {
        int pc = bC * 4 + wc;             // 0..63
        psum[(size_t)pc * 16384 + row] = s;
      }
    }
  }
}

// ---------- kernel 4: reduce 64 sumexp2 partials per row -> lse (natural log) ----------
__global__ void lse_reduce(const float* __restrict__ psum,
                           float* __restrict__ lse) {
  int row = blockIdx.x * 256 + threadIdx.x;
  float s = 0.f;
#pragma unroll 8
  for (int j = 0; j < 64; j++)
    s += psum[(size_t)j * 16384 + row];
  lse[row] = flog2(s) * LN2;
}

// ---------- kernel 5: CTC forward DP, one wave per sample ----------
// LINEAR-domain DP on raw-logit probabilities p = 2^(logit*L2E), with
// wave-uniform power-of-2 rescaling every 16 steps. Zero transcendentals
// in the serial loop. lse correction applied once at the end.
constexpr int DPD = 8;   // prefetch depth

__global__ __launch_bounds__(64) void ctc_dp(
    const float* __restrict__ plab, const float* __restrict__ lse,
    const int* __restrict__ extidx, const int* __restrict__ skipflag,
    const int* __restrict__ hlens, const int* __restrict__ ylens,
    float* __restrict__ out) {
  const int n    = blockIdx.x;
  const int lane = threadIdx.x;
  const int hlen = hlens[n];
  const int Ln   = 2 * ylens[n] + 1;
  const int sbase = lane * 4;   // states sbase..sbase+3; lane 63 also owns s=256

  // per-lane static DP metadata (even states are blanks since sbase is even)
  const int   e1  = extidx[n * Ll + sbase + 1];
  const int   e3  = extidx[n * Ll + sbase + 3];
  const float sk1 = skipflag[n * Ll + sbase + 1] ? 1.f : 0.f;
  const float sk3 = skipflag[n * Ll + sbase + 3] ? 1.f : 0.f;
  const float m0  = (sbase + 0 < Ln) ? 1.f : 0.f;
  const float m1  = (sbase + 1 < Ln) ? 1.f : 0.f;
  const float m2  = (sbase + 2 < Ln) ? 1.f : 0.f;
  const float m3  = (sbase + 3 < Ln) ? 1.f : 0.f;
  const float m4  = (lane == 63 && Ln == 257) ? 1.f : 0.f;

  const float* pl  = plab + (size_t)n * Tt * LS;
  const float* lsp = lse + n * Tt;

  // sum of lse over t < hlen (uniform across states -> applied once at end)
  float slse = 0.f;
  for (int t = lane; t < hlen; t += 64) slse += lsp[t];
#pragma unroll
  for (int off = 32; off; off >>= 1) slse += __shfl_xor(slse, off);

  // t = 0 init: alpha[0] = p_blank(0), alpha[1] = p_y1(0)
  float a0 = 0.f, a1 = 0.f, a2 = 0.f, a3 = 0.f, a4 = 0.f;
  if (lane == 0) { a0 = pl[0]; a1 = pl[e1]; }

  int sc = 0;   // accumulated log2 scale (true alpha = stored * 2^sc)

  auto step = [&](float pb, float p1, float p3) {
    float pm1 = __shfl_up(a3, 1);      // alpha[sbase-1]
    float pm2 = __shfl_up(a2, 1);      // alpha[sbase-2]
    pm1 = (lane == 0) ? 0.f : pm1;
    pm2 = (lane == 0) ? 0.f : pm2;
    float n4 = (a4 + a3) * pb * m4;                 // s=256 (blank), lane 63 only
    float n3 = (a3 + a2 + sk3 * a1)  * p3 * m3;     // odd (label)
    float n2 = (a2 + a1)             * pb * m2;     // even (blank)
    float n1 = (a1 + a0 + sk1 * pm2) * p1 * m1;     // odd (label)
    float n0 = (a0 + pm1)            * pb * m0;     // even (blank)
    a0 = n0; a1 = n1; a2 = n2; a3 = n3; a4 = n4;
  };

  auto rescale = [&]() {
    float mx = fmaxf(fmaxf(a0, a1), fmaxf(a2, a3));
    mx = fmaxf(mx, a4);
#pragma unroll
    for (int off = 32; off; off >>= 1) mx = fmaxf(mx, __shfl_xor(mx, off));
    int ee = (int)((__float_as_uint(mx) >> 23) & 0xff) - 127;   // floor(log2 mx)
    ee = (mx > 0.f) ? ee : 0;
    float s = __uint_as_float((unsigned)(127 - ee) << 23);      // 2^(-ee)
    sc += ee;
    a0 *= s; a1 *= s; a2 *= s; a3 *= s; a4 *= s;
  };

  // preload prefetch ring for t = 1..DPD (1 uniform blank + 2 gathers per row)
  float rb[DPD], r1[DPD], r3[DPD];
#pragma unroll
  for (int d = 0; d < DPD; d++) {
    int tt = 1 + d;
    rb[d] = pl[(size_t)tt * LS];
    r1[d] = pl[(size_t)tt * LS + e1];
    r3[d] = pl[(size_t)tt * LS + e3];
  }

  const int nfull = (hlen - 1) / DPD;
  for (int b = 0; b < nfull; b++) {
    const int t0 = 1 + b * DPD;
#pragma unroll
    for (int d = 0; d < DPD; d++) {
      float pb = rb[d], p1 = r1[d], p3 = r3[d];
      int tn = t0 + d + DPD;
      if (tn > Tt - 1) tn = Tt - 1;    // clamp keeps loads in-bounds
      rb[d] = pl[(size_t)tn * LS];
      r1[d] = pl[(size_t)tn * LS + e1];
      r3[d] = pl[(size_t)tn * LS + e3];
      step(pb, p1, p3);
    }
    if ((b & 1) || b == nfull - 1) rescale();   // every 16 steps + final block
  }
  // tail (< DPD steps): direct loads
  for (int t = 1 + nfull * DPD; t < hlen; t++) {
    step(pl[(size_t)t * LS], pl[(size_t)t * LS + e1], pl[(size_t)t * LS + e3]);
  }

  __shared__ float alf[264];
  alf[sbase + 0] = a0; alf[sbase + 1] = a1;
  alf[sbase + 2] = a2; alf[sbase + 3] = a3;
  if (lane == 63) alf[256] = a4;
  __syncthreads();
  if (lane == 0) {
    float sum = alf[Ln - 1] + alf[Ln - 2];
    float per = 0.f;
    if (sum > 0.f) {
      float llv = (flog2(sum) + (float)sc) * LN2 - slse;
      if (llv > -1e29f) per = -llv;
    }
    atomicAdd(out, per * (1.0f / 16.0f));
  }
}

// ---------- launcher ----------
extern "C" void kernel_launch(void* const* d_in, const int* in_sizes, int n_in,
                              void* d_out, int out_size, void* d_ws, size_t ws_size,
                              hipStream_t stream) {
  const float* hs    = (const float*)d_in[0];
  const int*   hlens = (const int*)d_in[1];
  const int*   ys    = (const int*)d_in[2];
  const int*   ylens = (const int*)d_in[3];
  const float* W     = (const float*)d_in[4];
  const float* bias  = (const float*)d_in[5];
  float*       out   = (float*)d_out;
  char*        ws    = (char*)d_ws;

  // workspace carve (bytes)
  const size_t off_hsb    = 0;                               // 16,777,216
  const size_t off_Wb     = off_hsb    + (size_t)Nn*Tt*IDIM*2;
  const size_t off_plab   = off_Wb     + (size_t)Vv*IDIM*2;  // 8,650,752
  const size_t off_psum   = off_plab   + (size_t)Nn*Tt*LS*4;
  const size_t off_lse    = off_psum   + (size_t)64*16384*4;
  const size_t off_labmap = off_lse    + (size_t)16384*4;
  const size_t off_extidx = off_labmap + (size_t)Nn*Vv*4;
  const size_t off_skip   = off_extidx + (size_t)((Nn*Ll*4 + 255) & ~255);

  bfu16* hsb    = (bfu16*)(ws + off_hsb);
  bfu16* Wb     = (bfu16*)(ws + off_Wb);
  float* plab   = (float*)(ws + off_plab);
  float* psum   = (float*)(ws + off_psum);
  float* lse    = (float*)(ws + off_lse);
  int*   labmap = (int*)(ws + off_labmap);
  int*   extidx = (int*)(ws + off_extidx);
  int*   skipf  = (int*)(ws + off_skip);

  convert_zero<<<2048, 256, 0, stream>>>(
      (const float4*)hs, (const float4*)W, (ushort4*)hsb, (ushort4*)Wb, out);
  build_labels<<<16, 256, 0, stream>>>(ys, labmap, extidx, skipf);
  gemm_lse<<<1024, 512, 0, stream>>>(hsb, Wb, bias, labmap, plab, psum);
  lse_reduce<<<64, 256, 0, stream>>>(psum, lse);
  ctc_dp<<<16, 64, 0, stream>>>(plab, lse, extidx, skipf, hlens, ylens, out);
}

// Round 10
// 205.185 us; speedup vs baseline: 1.2199x; 1.0287x over previous
//
#include <hip/hip_runtime.h>
#include <cstdint>
#include <cstddef>

// ---------- types ----------
using short8_t = __attribute__((ext_vector_type(8))) short;
using f32x4    = __attribute__((ext_vector_type(4))) float;
typedef unsigned short bfu16;

constexpr int   Nn   = 16;
constexpr int   Tt   = 1024;
constexpr int   IDIM = 512;
constexpr int   Vv   = 4096;
constexpr int   Ss   = 128;
constexpr int   Ll   = 2 * Ss + 1;   // 257
constexpr int   LS   = 132;          // plab row stride (pad 129 -> 132)
constexpr float NEGV = -1e30f;
constexpr float L2E  = 1.4426950408889634f;  // log2(e)
constexpr float LN2  = 0.6931471805599453f;  // ln(2)

// ---------- helpers ----------
__device__ __forceinline__ float fexp2(float x) { return __builtin_amdgcn_exp2f(x); }
__device__ __forceinline__ float flog2(float x) { return __builtin_amdgcn_logf(x); }

__device__ __forceinline__ bfu16 f2bf(float f) {
  unsigned int x = __float_as_uint(f);
  x = x + 0x7fffu + ((x >> 16) & 1u);   // RNE (inputs are finite normals)
  return (bfu16)(x >> 16);
}

__device__ __forceinline__ void async16(const void* g, void* l) {
  __builtin_amdgcn_global_load_lds(
      (__attribute__((address_space(1))) void*)(g),
      (__attribute__((address_space(3))) void*)(l), 16, 0, 0);
}

// ---------- kernel 1: fp32 -> bf16 convert + zero output ----------
__global__ void convert_zero(const float4* __restrict__ hs4,
                             const float4* __restrict__ W4,
                             ushort4* __restrict__ hsb4,
                             ushort4* __restrict__ Wb4,
                             float* __restrict__ out) {
  if (blockIdx.x == 0 && threadIdx.x == 0) out[0] = 0.f;
  const int HS4 = (Nn * Tt * IDIM) / 4;        // 2097152
  const int TOT = HS4 + (Vv * IDIM) / 4;       // +524288
  for (int i = blockIdx.x * 256 + threadIdx.x; i < TOT; i += gridDim.x * 256) {
    float4 f;
    if (i < HS4) f = hs4[i]; else f = W4[i - HS4];
    ushort4 o;
    o.x = f2bf(f.x); o.y = f2bf(f.y); o.z = f2bf(f.z); o.w = f2bf(f.w);
    if (i < HS4) hsb4[i] = o; else Wb4[i - HS4] = o;
  }
}

// ---------- kernel 2: build label map / extended sequence ----------
__global__ void build_labels(const int* __restrict__ ys,
                             int* __restrict__ labmap,
                             int* __restrict__ extidx,
                             int* __restrict__ skipflag) {
  const int n = blockIdx.x, tid = threadIdx.x;
  int* lm = labmap + n * Vv;
  for (int v = tid; v < Vv; v += 256) lm[v] = 0x7fffffff;
  __syncthreads();
  if (tid == 0) lm[0] = 0;                                  // blank -> slot 0
  if (tid < Ss) atomicMin(&lm[ys[n * Ss + tid]], tid + 1);  // canonical = first occurrence
  __syncthreads();
  for (int s = tid; s < Ll; s += 256) {
    int v = (s & 1) ? ys[n * Ss + ((s - 1) >> 1)] : 0;
    extidx[n * Ll + s] = lm[v];
    int allow = 0;
    if ((s & 1) && s >= 3) allow = (v != ys[n * Ss + ((s - 3) >> 1)]) ? 1 : 0;
    skipflag[n * Ll + s] = allow;
  }
  __syncthreads();
  for (int v = tid; v < Vv; v += 256)
    if (lm[v] == 0x7fffffff) lm[v] = -1;
}

// ---------- kernel 3: 256x256 BK=64 8-wave MFMA GEMM fused with lse + label scatter ----
// Quadrant-pipelined K-loop: 4 phases of 16 MFMA per K-tile, ds_reads issued one
// quadrant ahead, NO mid-tile barriers (LDS read-only within a tile), single
// vmcnt(0)+s_barrier per tile. Chunk-XOR swizzle (c ^= row&7) via pre-swizzled
// global source + swizzled ds_read chunk (0 bank conflicts, verified R7).
__global__ __launch_bounds__(512, 2) void gemm_lse(
    const bfu16* __restrict__ A,      // [16384][512] hs bf16
    const bfu16* __restrict__ B,      // [4096][512]  W  bf16 (B^T layout)
    const float* __restrict__ bias,   // [4096]
    const int*   __restrict__ labmap, // [16][4096]
    float* __restrict__ plab,         // [16384][LS]  exp2(logit*L2E) at label slots
    float* __restrict__ psum) {       // [64][16384]  sum of exp2(logit*L2E) partials
  __shared__ alignas(128) char ldsraw[131072];   // [buf][A/B][32KB]
  const int tid  = threadIdx.x;
  const int lane = tid & 63, wid = tid >> 6;     // 8 waves
  const int wr = wid >> 2, wc = wid & 3;         // 2M x 4N wave grid

  // bijective XCD swizzle (1024 % 8 == 0)
  const int flat = blockIdx.x;
  const int wg   = (flat & 7) * 128 + (flat >> 3);
  const int bR = wg >> 4, bC = wg & 15;
  const int rowbase = bR * 256, colbase = bC * 256;

  f32x4 acc[8][4];
#pragma unroll
  for (int m = 0; m < 8; m++)
#pragma unroll
    for (int n = 0; n < 4; n++) {
      f32x4 z = {0.f, 0.f, 0.f, 0.f};
      acc[m][n] = z;
    }

  // ---- staging setup: waves 0-3 stage A (64 rows each), 4-7 stage B ----
  const int  sw  = wid & 3;
  const bool isB = wid >= 4;
  const char* gsrc0 = (const char*)(isB ? (const void*)B : (const void*)A)
      + (size_t)((isB ? colbase : rowbase) + sw * 64 + (lane >> 3)) * (IDIM * 2)
      + (((lane & 7) ^ ((lane >> 3) & 7)) * 16);     // pre-swizzled source chunk
  char* ldst0 = ldsraw + (isB ? 32768 : 0) + sw * 8192;

  // ---- fragment-read setup ----
  const int fr = lane & 15;          // fragment row (A row / B col low bits)
  const int g  = lane >> 4;          // k-chunk 0..3 within K=32 half
  const int fx = fr & 7;             // row&7 for the XOR swizzle

  // epilogue metadata (prefetched; latency hidden under K-loop)
  const int nsamp = bR >> 2;         // 4 row-blocks (256) per sample (1024)
  const int* lm = labmap + nsamp * Vv;
  float bc[4];
  int   slot[4];
#pragma unroll
  for (int n = 0; n < 4; n++) {
    int c = colbase + wc * 64 + n * 16 + fr;
    bc[n]   = bias[c];
    slot[n] = lm[c];
  }

  auto stage = [&](int b, int t) {
#pragma unroll
    for (int i = 0; i < 8; ++i)
      async16(gsrc0 + (size_t)t * 128 + i * 8192, ldst0 + b * 65536 + i * 1024);
  };

  // prologue: tile 0 into buf 0
  stage(0, 0);
  asm volatile("s_waitcnt vmcnt(0)" ::: "memory");
  __builtin_amdgcn_s_barrier();

  int buf = 0;
  for (int t = 0; t < 8; ++t) {
    const char* Ab = ldsraw + buf * 65536;
    const char* Bb = Ab + 32768;
    if (t < 7) stage(buf ^ 1, t + 1);   // issue early: full tile of cover

    // quadrant-pipelined schedule
    short8_t a0[4], a1[4], a2[4], a3[4], b0[4], b1[4];
    // Q0 reads (A mh0 ks0 + B ks0)
#pragma unroll
    for (int m = 0; m < 4; m++)
      a0[m] = *(const short8_t*)(Ab + (wr * 128 + m * 16 + fr) * 128 + ((0 + g) ^ fx) * 16);
#pragma unroll
    for (int n = 0; n < 4; n++)
      b0[n] = *(const short8_t*)(Bb + (wc * 64 + n * 16 + fr) * 128 + ((0 + g) ^ fx) * 16);
    // Q1 reads (A mh1 ks0)
#pragma unroll
    for (int m = 0; m < 4; m++)
      a1[m] = *(const short8_t*)(Ab + (wr * 128 + (m + 4) * 16 + fr) * 128 + ((0 + g) ^ fx) * 16);

    // MFMA Q0
    __builtin_amdgcn_s_setprio(1);
#pragma unroll
    for (int m = 0; m < 4; m++)
#pragma unroll
      for (int n = 0; n < 4; n++)
        acc[m][n] = __builtin_amdgcn_mfma_f32_16x16x32_bf16(a0[m], b0[n], acc[m][n], 0, 0, 0);
    __builtin_amdgcn_s_setprio(0);

    // Q2 reads (A mh0 ks1 + B ks1)
#pragma unroll
    for (int m = 0; m < 4; m++)
      a2[m] = *(const short8_t*)(Ab + (wr * 128 + m * 16 + fr) * 128 + ((4 + g) ^ fx) * 16);
#pragma unroll
    for (int n = 0; n < 4; n++)
      b1[n] = *(const short8_t*)(Bb + (wc * 64 + n * 16 + fr) * 128 + ((4 + g) ^ fx) * 16);

    // MFMA Q1
    __builtin_amdgcn_s_setprio(1);
#pragma unroll
    for (int m = 0; m < 4; m++)
#pragma unroll
      for (int n = 0; n < 4; n++)
        acc[m + 4][n] = __builtin_amdgcn_mfma_f32_16x16x32_bf16(a1[m], b0[n], acc[m + 4][n], 0, 0, 0);
    __builtin_amdgcn_s_setprio(0);

    // Q3 reads (A mh1 ks1)
#pragma unroll
    for (int m = 0; m < 4; m++)
      a3[m] = *(const short8_t*)(Ab + (wr * 128 + (m + 4) * 16 + fr) * 128 + ((4 + g) ^ fx) * 16);

    // MFMA Q2
    __builtin_amdgcn_s_setprio(1);
#pragma unroll
    for (int m = 0; m < 4; m++)
#pragma unroll
      for (int n = 0; n < 4; n++)
        acc[m][n] = __builtin_amdgcn_mfma_f32_16x16x32_bf16(a2[m], b1[n], acc[m][n], 0, 0, 0);
    __builtin_amdgcn_s_setprio(0);

    // MFMA Q3
    __builtin_amdgcn_s_setprio(1);
#pragma unroll
    for (int m = 0; m < 4; m++)
#pragma unroll
      for (int n = 0; n < 4; n++)
        acc[m + 4][n] = __builtin_amdgcn_mfma_f32_16x16x32_bf16(a3[m], b1[n], acc[m + 4][n], 0, 0, 0);
    __builtin_amdgcn_s_setprio(0);

    asm volatile("s_waitcnt vmcnt(0)" ::: "memory");   // next tile resident
    __builtin_amdgcn_s_barrier();
    buf ^= 1;
  }

  // ---- epilogue: bias, label scatter (exp2'd), max-free sumexp2 partials ----
  // (logits for this problem are bounded |v| < ~10; exp2 sums fit fp32 easily)
  const int g4 = g * 4;
#pragma unroll
  for (int m = 0; m < 8; m++) {
#pragma unroll
    for (int r = 0; r < 4; r++) {
      int row = rowbase + wr * 128 + m * 16 + g4 + r;
      float e0 = fexp2((acc[m][0][r] + bc[0]) * L2E);
      float e1 = fexp2((acc[m][1][r] + bc[1]) * L2E);
      float e2 = fexp2((acc[m][2][r] + bc[2]) * L2E);
      float e3 = fexp2((acc[m][3][r] + bc[3]) * L2E);
      if (slot[0] >= 0) plab[(size_t)row * LS + slot[0]] = e0;
      if (slot[1] >= 0) plab[(size_t)row * LS + slot[1]] = e1;
      if (slot[2] >= 0) plab[(size_t)row * LS + slot[2]] = e2;
      if (slot[3] >= 0) plab[(size_t)row * LS + slot[3]] = e3;
      float s = (e0 + e1) + (e2 + e3);
      s += __shfl_xor(s, 1);
      s += __shfl_xor(s, 2);
      s += __shfl_xor(s, 4);
      s += __shfl_xor(s, 8);
      if (fr == 0) {
        int pc = bC * 4 + wc;             // 0..63
        psum[(size_t)pc * 16384 + row] = s;
      }
    }
  }
}

// ---------- kernel 4: reduce 64 sumexp2 partials per row -> lse (natural log) ----------
__global__ void lse_reduce(const float* __restrict__ psum,
                           float* __restrict__ lse) {
  int row = blockIdx.x * 256 + threadIdx.x;
  float s = 0.f;
#pragma unroll 8
  for (int j = 0; j < 64; j++)
    s += psum[(size_t)j * 16384 + row];
  lse[row] = flog2(s) * LN2;
}

// ---------- kernel 5: CTC forward DP, one wave per sample ----------
// LINEAR-domain, 2-step-batched: one shfl round (4 independent shfls) per TWO
// time-steps; halo state h1 computed redundantly per lane. Validity masks are
// applied ONLY inside rescale() (every 16 steps): garbage states s>=Ln never
// flow downward, but left unmasked they dominate the rescale max and underflow
// the valid states (R9 failure) — periodic zeroing is exactly equivalent for
// the valid lattice and keeps the max honest.
constexpr int DP2 = 4;   // pair prefetch depth (8 rows ahead)

__global__ __launch_bounds__(64) void ctc_dp(
    const float* __restrict__ plab, const float* __restrict__ lse,
    const int* __restrict__ extidx, const int* __restrict__ skipflag,
    const int* __restrict__ hlens, const int* __restrict__ ylens,
    float* __restrict__ out) {
  const int n    = blockIdx.x;
  const int lane = threadIdx.x;
  const int hlen = hlens[n];
  const int Ln   = 2 * ylens[n] + 1;
  const int sbase = lane * 4;   // states sbase..sbase+3; lane 63 also owns s=256

  const int   e1  = extidx[n * Ll + sbase + 1];
  const int   e3  = extidx[n * Ll + sbase + 3];
  const float sk1 = skipflag[n * Ll + sbase + 1] ? 1.f : 0.f;
  const float sk3 = skipflag[n * Ll + sbase + 3] ? 1.f : 0.f;
  const float skh = (lane > 0 && skipflag[n * Ll + sbase - 1]) ? 1.f : 0.f;
  const bool  l0  = (lane == 0);
  // validity masks (applied only at rescale)
  const float m0  = (sbase + 0 < Ln) ? 1.f : 0.f;
  const float m1  = (sbase + 1 < Ln) ? 1.f : 0.f;
  const float m2  = (sbase + 2 < Ln) ? 1.f : 0.f;
  const float m3  = (sbase + 3 < Ln) ? 1.f : 0.f;
  const float m4  = (lane == 63 && Ln == 257) ? 1.f : 0.f;

  const float* pl  = plab + (size_t)n * Tt * LS;
  const float* lsp = lse + n * Tt;

  // sum of lse over t < hlen (16 independent loads, one latency exposure)
  float slse = 0.f;
#pragma unroll
  for (int j = 0; j < 16; j++) {
    int t = lane + 64 * j;
    float v = lsp[t];
    slse += (t < hlen) ? v : 0.f;
  }
#pragma unroll
  for (int off = 32; off; off >>= 1) slse += __shfl_xor(slse, off);

  // t = 0 init: alpha[0] = p_blank(0), alpha[1] = p_y1(0)
  float a0 = 0.f, a1 = 0.f, a2 = 0.f, a3 = 0.f, a4 = 0.f;
  if (l0) { a0 = pl[0]; a1 = pl[e1]; }

  int sc = 0;   // accumulated log2 scale (true alpha = stored * 2^sc)

  // two DP steps with ONE shfl round (exact 2x unroll of the reference step)
  auto pair2 = [&](float pbA, float p1A, float p3A,
                   float pbB, float p1B, float p3B) {
    float pa3 = __shfl_up(a3, 1);      // alpha_t[sbase-1]
    float pa2 = __shfl_up(a2, 1);      // alpha_t[sbase-2]
    float pa1 = __shfl_up(a1, 1);      // alpha_t[sbase-3]
    float prA = __shfl_up(p3A, 1);     // p_{t+1}(label at state sbase-1)
    pa3 = l0 ? 0.f : pa3;
    pa2 = l0 ? 0.f : pa2;
    pa1 = l0 ? 0.f : pa1;
    // step A: t -> t+1; halo h1 = alpha_{t+1}[sbase-1] (neighbor's s3)
    float h1 = (pa3 + pa2 + skh * pa1) * prA;
    float s4 = (a4 + a3) * pbA;
    float s3 = (a3 + a2 + sk3 * a1) * p3A;
    float s2 = (a2 + a1) * pbA;
    float s1 = (a1 + a0 + sk1 * pa3) * p1A;
    float s0 = (a0 + pa3) * pbA;
    // step B: t+1 -> t+2 (all inputs local)
    a4 = (s4 + s3) * pbB;
    a3 = (s3 + s2 + sk3 * s1) * p3B;
    a2 = (s2 + s1) * pbB;
    a1 = (s1 + s0 + sk1 * h1) * p1B;
    a0 = (s0 + h1) * pbB;
  };

  auto step1 = [&](float pb, float p1, float p3) {
    float pm1 = __shfl_up(a3, 1);      // alpha[sbase-1]
    pm1 = l0 ? 0.f : pm1;
    float n4 = (a4 + a3) * pb;
    float n3 = (a3 + a2 + sk3 * a1) * p3;
    float n2 = (a2 + a1) * pb;
    float n1 = (a1 + a0 + sk1 * pm1) * p1;
    float n0 = (a0 + pm1) * pb;
    a0 = n0; a1 = n1; a2 = n2; a3 = n3; a4 = n4;
  };

  auto rescale = [&]() {
    // mask garbage states (s >= Ln) BEFORE the max: they never flow down into
    // valid states, but unmasked they dominate mx and underflow the readout.
    a0 *= m0; a1 *= m1; a2 *= m2; a3 *= m3; a4 *= m4;
    float mx = fmaxf(fmaxf(a0, a1), fmaxf(a2, a3));
    mx = fmaxf(mx, a4);
#pragma unroll
    for (int off = 32; off; off >>= 1) mx = fmaxf(mx, __shfl_xor(mx, off));
    int ee = (int)((__float_as_uint(mx) >> 23) & 0xff) - 127;   // floor(log2 mx)
    ee = (mx > 0.f) ? ee : 0;
    float s = __uint_as_float((unsigned)(127 - ee) << 23);      // 2^(-ee)
    sc += ee;
    a0 *= s; a1 *= s; a2 *= s; a3 *= s; a4 *= s;
  };

  const int nsteps = hlen - 1;        // steps consume rows 1..hlen-1
  const int npairs = nsteps >> 1;

  // prefetch ring: pair j holds rows tA=1+2j, tB=2+2j
  float rbA[DP2], r1A[DP2], r3A[DP2], rbB[DP2], r1B[DP2], r3B[DP2];
#pragma unroll
  for (int d = 0; d < DP2; d++) {
    int tA = 1 + 2 * d, tB = tA + 1;
    rbA[d] = pl[(size_t)tA * LS];
    r1A[d] = pl[(size_t)tA * LS + e1];
    r3A[d] = pl[(size_t)tA * LS + e3];
    rbB[d] = pl[(size_t)tB * LS];
    r1B[d] = pl[(size_t)tB * LS + e1];
    r3B[d] = pl[(size_t)tB * LS + e3];
  }

  const int nblk = npairs / DP2;
  for (int b = 0; b < nblk; b++) {
#pragma unroll
    for (int d = 0; d < DP2; d++) {
      float pbA = rbA[d], p1A = r1A[d], p3A = r3A[d];
      float pbB = rbB[d], p1B = r1B[d], p3B = r3B[d];
      int jn = b * DP2 + d + DP2;     // prefetch pair jn (8 rows ahead)
      int tA = 1 + 2 * jn, tB = tA + 1;
      if (tA > Tt - 1) tA = Tt - 1;   // clamp keeps loads in-bounds
      if (tB > Tt - 1) tB = Tt - 1;
      rbA[d] = pl[(size_t)tA * LS];
      r1A[d] = pl[(size_t)tA * LS + e1];
      r3A[d] = pl[(size_t)tA * LS + e3];
      rbB[d] = pl[(size_t)tB * LS];
      r1B[d] = pl[(size_t)tB * LS + e1];
      r3B[d] = pl[(size_t)tB * LS + e3];
      pair2(pbA, p1A, p3A, pbB, p1B, p3B);
    }
    if ((b & 1) || b == nblk - 1) rescale();   // every 16 steps + final block
  }
  // tail pairs (< DP2): direct loads
  for (int j = nblk * DP2; j < npairs; j++) {
    int tA = 1 + 2 * j, tB = tA + 1;
    pair2(pl[(size_t)tA * LS], pl[(size_t)tA * LS + e1], pl[(size_t)tA * LS + e3],
          pl[(size_t)tB * LS], pl[(size_t)tB * LS + e1], pl[(size_t)tB * LS + e3]);
  }
  // tail single step (odd step count)
  if (nsteps & 1) {
    int t = nsteps;                   // = hlen-1
    step1(pl[(size_t)t * LS], pl[(size_t)t * LS + e1], pl[(size_t)t * LS + e3]);
  }
  rescale();                          // final mask + normalize before readout

  __shared__ float alf[264];
  alf[sbase + 0] = a0; alf[sbase + 1] = a1;
  alf[sbase + 2] = a2; alf[sbase + 3] = a3;
  if (lane == 63) alf[256] = a4;
  __syncthreads();
  if (l0) {
    float sum = alf[Ln - 1] + alf[Ln - 2];
    float per = 0.f;
    if (sum > 0.f) {
      float llv = (flog2(sum) + (float)sc) * LN2 - slse;
      if (llv > -1e29f) per = -llv;
    }
    atomicAdd(out, per * (1.0f / 16.0f));
  }
}

// ---------- launcher ----------
extern "C" void kernel_launch(void* const* d_in, const int* in_sizes, int n_in,
                              void* d_out, int out_size, void* d_ws, size_t ws_size,
                              hipStream_t stream) {
  const float* hs    = (const float*)d_in[0];
  const int*   hlens = (const int*)d_in[1];
  const int*   ys    = (const int*)d_in[2];
  const int*   ylens = (const int*)d_in[3];
  const float* W     = (const float*)d_in[4];
  const float* bias  = (const float*)d_in[5];
  float*       out   = (float*)d_out;
  char*        ws    = (char*)d_ws;

  // workspace carve (bytes)
  const size_t off_hsb    = 0;                               // 16,777,216
  const size_t off_Wb     = off_hsb    + (size_t)Nn*Tt*IDIM*2;
  const size_t off_plab   = off_Wb     + (size_t)Vv*IDIM*2;  // 8,650,752
  const size_t off_psum   = off_plab   + (size_t)Nn*Tt*LS*4;
  const size_t off_lse    = off_psum   + (size_t)64*16384*4;
  const size_t off_labmap = off_lse    + (size_t)16384*4;
  const size_t off_extidx = off_labmap + (size_t)Nn*Vv*4;
  const size_t off_skip   = off_extidx + (size_t)((Nn*Ll*4 + 255) & ~255);

  bfu16* hsb    = (bfu16*)(ws + off_hsb);
  bfu16* Wb     = (bfu16*)(ws + off_Wb);
  float* plab   = (float*)(ws + off_plab);
  float* psum   = (float*)(ws + off_psum);
  float* lse    = (float*)(ws + off_lse);
  int*   labmap = (int*)(ws + off_labmap);
  int*   extidx = (int*)(ws + off_extidx);
  int*   skipf  = (int*)(ws + off_skip);

  convert_zero<<<2048, 256, 0, stream>>>(
      (const float4*)hs, (const float4*)W, (ushort4*)hsb, (ushort4*)Wb, out);
  build_labels<<<16, 256, 0, stream>>>(ys, labmap, extidx, skipf);
  gemm_lse<<<1024, 512, 0, stream>>>(hsb, Wb, bias, labmap, plab, psum);
  lse_reduce<<<64, 256, 0, stream>>>(psum, lse);
  ctc_dp<<<16, 64, 0, stream>>>(plab, lse, extidx, skipf, hlens, ylens, out);
}